// Round 1
// baseline (745.191 us; speedup 1.0000x reference)
//
#include <hip/hip_runtime.h>
#include <math.h>

#define NN   4096
#define DIM  256
#define NE   131072
#define NH   4
#define DH   64
#define F1D  128
#define NG   16
#define AD   32

enum { EPI_BIAS = 0, EPI_BNELU = 1, EPI_BIAS_ELU = 2, EPI_BIAS_RES = 3 };

// ---------------- CSR build (deterministic counts; per-node sum order is
// whatever fill order atomics give — fp reorder noise only) ----------------
__global__ void csr_count(const int* __restrict__ dst, int* __restrict__ cnt) {
    int e = blockIdx.x * 256 + threadIdx.x;
    atomicAdd(&cnt[dst[e]], 1);
}

__global__ void csr_scan(const int* __restrict__ cnt, int* __restrict__ off) {
    int lane = threadIdx.x;             // 64 lanes, each owns 64 nodes
    int base = lane * (NN / 64);
    int s = 0;
    for (int i = 0; i < NN / 64; ++i) s += cnt[base + i];
    int acc = s;
    #pragma unroll
    for (int o = 1; o < 64; o <<= 1) {
        int t = __shfl_up(acc, o);
        if (lane >= o) acc += t;
    }
    int run = acc - s;                  // exclusive prefix
    for (int i = 0; i < NN / 64; ++i) { off[base + i] = run; run += cnt[base + i]; }
    if (lane == 63) off[NN] = run;
}

__global__ void csr_fill(const int* __restrict__ dst, const int* __restrict__ off,
                         int* __restrict__ cur, int* __restrict__ elist) {
    int e = blockIdx.x * 256 + threadIdx.x;
    int d = dst[e];
    int pos = off[d] + atomicAdd(&cur[d], 1);
    elist[pos] = e;
}

// ---------------- neighbor aggregation: one block per node ----------------
template<bool LAST>
__global__ __launch_bounds__(256) void agg_kernel(
    const float* __restrict__ x, const int* __restrict__ src,
    const float* __restrict__ eattr, const int* __restrict__ off,
    const int* __restrict__ elist, float* __restrict__ agg)
{
    int n = blockIdx.x;
    int d = threadIdx.x;
    int j0 = off[n], j1 = off[n + 1];
    float acc = 0.f;
    for (int j = j0; j < j1; ++j) {
        int e = elist[j];
        int s = src[e];
        float w = LAST ? eattr[e] : 1.f;
        acc = fmaf(x[(size_t)s * DIM + d], w, acc);
    }
    agg[(size_t)n * DIM + d] = acc;
}

// ---------------- fp32 tiled GEMM, 64x64 tile, BK=16, 4x4 microtile -------
// out[N x M] = A0[N x K] @ B0[K x M] (+ A1 @ B1) + bias, then epilogue.
template<int EPI, bool DUAL>
__global__ __launch_bounds__(256) void gemm_kernel(
    const float* __restrict__ A0, const float* __restrict__ B0,
    const float* __restrict__ A1, const float* __restrict__ B1,
    const float* __restrict__ bias,
    const float* __restrict__ gamma, const float* __restrict__ beta,
    const float* __restrict__ bnmean, const float* __restrict__ bnvar,
    const float* __restrict__ resid,
    float* __restrict__ out, int K, int M)
{
    __shared__ float As[16][68];   // [kk][row], pad 68 -> conflict-free stores
    __shared__ float Bs[16][64];   // [kk][col]

    const int tid  = threadIdx.x;
    const int row0 = blockIdx.y * 64;
    const int col0 = blockIdx.x * 64;
    const int ty = tid >> 4;       // 0..15 -> rows ty*4..
    const int tx = tid & 15;       // 0..15 -> cols tx*4..
    const int lrow = tid >> 2;     // A-load row 0..63
    const int lk4  = (tid & 3) * 4;
    const int bk   = tid >> 4;     // B-load k-row 0..15
    const int bc4  = (tid & 15) * 4;

    float acc[4][4] = {};
    const int kTot = DUAL ? 2 * K : K;
    for (int k0 = 0; k0 < kTot; k0 += 16) {
        const bool ph1 = DUAL && (k0 >= K);
        const float* A = ph1 ? A1 : A0;
        const float* B = ph1 ? B1 : B0;
        const int kb = ph1 ? (k0 - K) : k0;
        float4 av = *(const float4*)&A[(size_t)(row0 + lrow) * K + kb + lk4];
        float4 bv = *(const float4*)&B[(size_t)(kb + bk) * M + col0 + bc4];
        __syncthreads();
        As[lk4 + 0][lrow] = av.x;
        As[lk4 + 1][lrow] = av.y;
        As[lk4 + 2][lrow] = av.z;
        As[lk4 + 3][lrow] = av.w;
        *(float4*)&Bs[bk][bc4] = bv;
        __syncthreads();
        #pragma unroll
        for (int kk = 0; kk < 16; ++kk) {
            float4 a = *(const float4*)&As[kk][ty * 4];
            float4 b = *(const float4*)&Bs[kk][tx * 4];
            acc[0][0] = fmaf(a.x, b.x, acc[0][0]);
            acc[0][1] = fmaf(a.x, b.y, acc[0][1]);
            acc[0][2] = fmaf(a.x, b.z, acc[0][2]);
            acc[0][3] = fmaf(a.x, b.w, acc[0][3]);
            acc[1][0] = fmaf(a.y, b.x, acc[1][0]);
            acc[1][1] = fmaf(a.y, b.y, acc[1][1]);
            acc[1][2] = fmaf(a.y, b.z, acc[1][2]);
            acc[1][3] = fmaf(a.y, b.w, acc[1][3]);
            acc[2][0] = fmaf(a.z, b.x, acc[2][0]);
            acc[2][1] = fmaf(a.z, b.y, acc[2][1]);
            acc[2][2] = fmaf(a.z, b.z, acc[2][2]);
            acc[2][3] = fmaf(a.z, b.w, acc[2][3]);
            acc[3][0] = fmaf(a.w, b.x, acc[3][0]);
            acc[3][1] = fmaf(a.w, b.y, acc[3][1]);
            acc[3][2] = fmaf(a.w, b.z, acc[3][2]);
            acc[3][3] = fmaf(a.w, b.w, acc[3][3]);
        }
    }
    #pragma unroll
    for (int i = 0; i < 4; ++i) {
        const int r = row0 + ty * 4 + i;
        #pragma unroll
        for (int j = 0; j < 4; ++j) {
            const int c = col0 + tx * 4 + j;
            float v = acc[i][j] + bias[c];
            if (EPI == EPI_BNELU) {
                v = gamma[c] * (v - bnmean[c]) * rsqrtf(bnvar[c] + 1e-5f) + beta[c];
                v = v > 0.f ? v : expm1f(v);
            } else if (EPI == EPI_BIAS_ELU) {
                v = v > 0.f ? v : expm1f(v);
            } else if (EPI == EPI_BIAS_RES) {
                v += resid[(size_t)r * M + c];
            }
            out[(size_t)r * M + c] = v;
        }
    }
}

// ---------------- flash attention, fp32, QB=32 q-rows per block -----------
// grid (NN/32, NH), 256 threads. Online softmax state lives in Ps side cols:
// Ps[r][64]=running max, Ps[r][65]=denominator, Ps[r][66]=rescale factor.
#define QB 32
__global__ __launch_bounds__(256) void attn_kernel(
    const float* __restrict__ q, const float* __restrict__ k,
    const float* __restrict__ v, float* __restrict__ o)
{
    __shared__ float QsT[64][32];    // [d][qrow], q pre-scaled by 1/8
    __shared__ float KsT[64][64];    // [d][krow]
    __shared__ float Vs[64][68];     // [krow][d], pad 68
    __shared__ float Ps[QB][68];     // [qrow][krow] + state cols 64..66

    const int tid = threadIdx.x;
    const int h  = blockIdx.y;
    const int q0 = blockIdx.x * QB;

    {   // load+transpose Q, fold in 1/sqrt(dh)=0.125 exactly
        const int r = tid >> 3, seg = tid & 7;
        const float* qp = q + (size_t)(q0 + r) * DIM + h * DH + seg * 8;
        float4 a = ((const float4*)qp)[0];
        float4 b = ((const float4*)qp)[1];
        const int d0 = seg * 8;
        QsT[d0 + 0][r] = a.x * 0.125f; QsT[d0 + 1][r] = a.y * 0.125f;
        QsT[d0 + 2][r] = a.z * 0.125f; QsT[d0 + 3][r] = a.w * 0.125f;
        QsT[d0 + 4][r] = b.x * 0.125f; QsT[d0 + 5][r] = b.y * 0.125f;
        QsT[d0 + 6][r] = b.z * 0.125f; QsT[d0 + 7][r] = b.w * 0.125f;
    }
    if (tid < QB) { Ps[tid][64] = -3.0e38f; Ps[tid][65] = 0.f; }

    float oacc[8] = {};
    const int pr = tid >> 3;        // PV: row 0..31
    const int pseg = tid & 7;       // PV: dims pseg*8..
    const int lr = tid >> 2;        // load: key row 0..63
    const int lseg = tid & 3;       // load: 16 dims
    const int sy = tid >> 4;        // S: rows sy*2, sy*2+1
    const int sx = tid & 15;        // S: cols sx*4..

    for (int kt = 0; kt < NN / 64; ++kt) {
        const int kbase = kt * 64;
        __syncthreads();            // prev tile's PV done
        {   // load K (transposed) and V (direct)
            const float* kp = k + (size_t)(kbase + lr) * DIM + h * DH + lseg * 16;
            float4 ka = ((const float4*)kp)[0];
            float4 kb = ((const float4*)kp)[1];
            float4 kc = ((const float4*)kp)[2];
            float4 kd = ((const float4*)kp)[3];
            const int c0 = lseg * 16;
            KsT[c0 +  0][lr] = ka.x; KsT[c0 +  1][lr] = ka.y;
            KsT[c0 +  2][lr] = ka.z; KsT[c0 +  3][lr] = ka.w;
            KsT[c0 +  4][lr] = kb.x; KsT[c0 +  5][lr] = kb.y;
            KsT[c0 +  6][lr] = kb.z; KsT[c0 +  7][lr] = kb.w;
            KsT[c0 +  8][lr] = kc.x; KsT[c0 +  9][lr] = kc.y;
            KsT[c0 + 10][lr] = kc.z; KsT[c0 + 11][lr] = kc.w;
            KsT[c0 + 12][lr] = kd.x; KsT[c0 + 13][lr] = kd.y;
            KsT[c0 + 14][lr] = kd.z; KsT[c0 + 15][lr] = kd.w;
            const float* vp = v + (size_t)(kbase + lr) * DIM + h * DH + lseg * 16;
            float4 va = ((const float4*)vp)[0];
            float4 vb = ((const float4*)vp)[1];
            float4 vc = ((const float4*)vp)[2];
            float4 vd = ((const float4*)vp)[3];
            *(float4*)&Vs[lr][c0 +  0] = va;
            *(float4*)&Vs[lr][c0 +  4] = vb;
            *(float4*)&Vs[lr][c0 +  8] = vc;
            *(float4*)&Vs[lr][c0 + 12] = vd;
        }
        __syncthreads();
        // ---- S = Q K^T (2 rows x 4 cols per thread) ----
        float sc[8] = {};
        #pragma unroll 8
        for (int d = 0; d < 64; ++d) {
            const float2 qd = *(const float2*)&QsT[d][sy * 2];
            const float4 kd = *(const float4*)&KsT[d][sx * 4];
            sc[0] = fmaf(qd.x, kd.x, sc[0]);
            sc[1] = fmaf(qd.x, kd.y, sc[1]);
            sc[2] = fmaf(qd.x, kd.z, sc[2]);
            sc[3] = fmaf(qd.x, kd.w, sc[3]);
            sc[4] = fmaf(qd.y, kd.x, sc[4]);
            sc[5] = fmaf(qd.y, kd.y, sc[5]);
            sc[6] = fmaf(qd.y, kd.z, sc[6]);
            sc[7] = fmaf(qd.y, kd.w, sc[7]);
        }
        // ---- online softmax update (per row: 16 lanes, same wave) ----
        #pragma unroll
        for (int i = 0; i < 2; ++i) {
            const float* s4 = &sc[i * 4];
            float rm = fmaxf(fmaxf(s4[0], s4[1]), fmaxf(s4[2], s4[3]));
            #pragma unroll
            for (int mm = 1; mm < 16; mm <<= 1) rm = fmaxf(rm, __shfl_xor(rm, mm));
            const int r = sy * 2 + i;
            const float mold = Ps[r][64];
            const float mnew = fmaxf(mold, rm);
            const float p0 = expf(s4[0] - mnew);
            const float p1 = expf(s4[1] - mnew);
            const float p2 = expf(s4[2] - mnew);
            const float p3 = expf(s4[3] - mnew);
            float psum = (p0 + p1) + (p2 + p3);
            #pragma unroll
            for (int mm = 1; mm < 16; mm <<= 1) psum += __shfl_xor(psum, mm);
            float4 pv = make_float4(p0, p1, p2, p3);
            *(float4*)&Ps[r][sx * 4] = pv;
            if (sx == 0) {
                const float fsc = expf(mold - mnew);
                Ps[r][64] = mnew;
                Ps[r][65] = Ps[r][65] * fsc + psum;
                Ps[r][66] = fsc;
            }
        }
        __syncthreads();
        // ---- PV accumulate (1 row x 8 dims per thread) ----
        const float fsc = Ps[pr][66];
        #pragma unroll
        for (int j = 0; j < 8; ++j) oacc[j] *= fsc;
        #pragma unroll 4
        for (int kk = 0; kk < 64; ++kk) {
            const float p = Ps[pr][kk];
            const float4 va = *(const float4*)&Vs[kk][pseg * 8];
            const float4 vb = *(const float4*)&Vs[kk][pseg * 8 + 4];
            oacc[0] = fmaf(p, va.x, oacc[0]);
            oacc[1] = fmaf(p, va.y, oacc[1]);
            oacc[2] = fmaf(p, va.z, oacc[2]);
            oacc[3] = fmaf(p, va.w, oacc[3]);
            oacc[4] = fmaf(p, vb.x, oacc[4]);
            oacc[5] = fmaf(p, vb.y, oacc[5]);
            oacc[6] = fmaf(p, vb.z, oacc[6]);
            oacc[7] = fmaf(p, vb.w, oacc[7]);
        }
    }
    const float inv = 1.f / Ps[pr][65];
    float* op = o + (size_t)(q0 + pr) * DIM + h * DH + pseg * 8;
    float4 r0 = make_float4(oacc[0] * inv, oacc[1] * inv, oacc[2] * inv, oacc[3] * inv);
    float4 r1 = make_float4(oacc[4] * inv, oacc[5] * inv, oacc[6] * inv, oacc[7] * inv);
    ((float4*)op)[0] = r0;
    ((float4*)op)[1] = r1;
}

// ---------------- per-node group adapter: 1 wave per node -----------------
__global__ __launch_bounds__(64) void adapter_kernel(
    const float* __restrict__ feats, const int* __restrict__ grp,
    const float* __restrict__ AW1, const float* __restrict__ Ab1,
    const float* __restrict__ AW2, const float* __restrict__ Ab2,
    float* __restrict__ out)
{
    const int n = blockIdx.x;
    const int lane = threadIdx.x;
    __shared__ float f[F1D];
    f[lane]      = feats[(size_t)n * F1D + lane];
    f[lane + 64] = feats[(size_t)n * F1D + 64 + lane];
    __syncthreads();
    const int g = grp[n];
    const float* W1 = AW1 + (size_t)g * F1D * AD;
    const int a = lane & 31;
    const int half = lane >> 5;     // lanes 0..31 do d<64, 32..63 do d>=64
    float hsum = 0.f;
    for (int d = 0; d < 64; ++d)
        hsum = fmaf(f[half * 64 + d], W1[(half * 64 + d) * AD + a], hsum);
    hsum += __shfl_xor(hsum, 32);
    hsum = fmaxf(hsum + Ab1[g * AD + a], 0.f);
    float p = hsum * AW2[g * AD + a];
    #pragma unroll
    for (int mm = 1; mm < 32; mm <<= 1) p += __shfl_xor(p, mm);
    if (lane == 0) out[n] = p + Ab2[g];
}

// ---------------- host-side orchestration ----------------
extern "C" void kernel_launch(void* const* d_in, const int* in_sizes, int n_in,
                              void* d_out, int out_size, void* d_ws, size_t ws_size,
                              hipStream_t stream)
{
    const float* x_in   = (const float*)d_in[0];
    const float* eattr  = (const float*)d_in[1];
    const float* Wself  = (const float*)d_in[2];
    const float* Wnbr   = (const float*)d_in[3];
    const float* convb  = (const float*)d_in[4];
    const float* gamma  = (const float*)d_in[5];
    const float* beta   = (const float*)d_in[6];
    const float* bnmean = (const float*)d_in[7];
    const float* bnvar  = (const float*)d_in[8];
    const float* Wqkv   = (const float*)d_in[9];
    const float* bqkv   = (const float*)d_in[10];
    const float* Wo     = (const float*)d_in[11];
    const float* bo     = (const float*)d_in[12];
    const float* fc1W   = (const float*)d_in[13];
    const float* fc1b   = (const float*)d_in[14];
    const float* AW1    = (const float*)d_in[15];
    const float* Ab1    = (const float*)d_in[16];
    const float* AW2    = (const float*)d_in[17];
    const float* Ab2    = (const float*)d_in[18];
    const int*   eidx   = (const int*)d_in[19];
    const int*   grp    = (const int*)d_in[20];
    const int* srcArr = eidx;
    const int* dstArr = eidx + NE;

    float* fws = (float*)d_ws;
    const size_t NM = (size_t)NN * DIM;
    float* bufA  = fws;            // x after layer0 / layer2
    float* bufB  = fws + NM;       // agg scratch, later post-residual x
    float* bufC  = fws + 2 * NM;   // x after layer1, later attention o
    float* bufQ  = fws + 3 * NM;
    float* bufK  = fws + 4 * NM;
    float* bufV  = fws + 5 * NM;
    float* feats = fws + 6 * NM;   // NN x F1D
    int* iws   = (int*)(fws + 6 * NM + (size_t)NN * F1D);
    int* off   = iws;                    // NN+1
    int* cur   = iws + NN + 1;           // NN
    int* elist = iws + 2 * NN + 1;       // NE
    float* outp = (float*)d_out;

    // CSR build
    hipMemsetAsync(cur, 0, NN * sizeof(int), stream);
    csr_count<<<NE / 256, 256, 0, stream>>>(dstArr, cur);
    csr_scan<<<1, 64, 0, stream>>>(cur, off);
    hipMemsetAsync(cur, 0, NN * sizeof(int), stream);
    csr_fill<<<NE / 256, 256, 0, stream>>>(dstArr, off, cur, elist);

    const dim3 gg(DIM / 64, NN / 64);

    // conv layer 0: x_in -> bufA
    agg_kernel<false><<<NN, 256, 0, stream>>>(x_in, srcArr, eattr, off, elist, bufB);
    gemm_kernel<EPI_BNELU, true><<<gg, 256, 0, stream>>>(
        x_in, Wself, bufB, Wnbr, convb, gamma, beta, bnmean, bnvar,
        nullptr, bufA, DIM, DIM);
    // conv layer 1: bufA -> bufC
    agg_kernel<false><<<NN, 256, 0, stream>>>(bufA, srcArr, eattr, off, elist, bufB);
    gemm_kernel<EPI_BNELU, true><<<gg, 256, 0, stream>>>(
        bufA, Wself + DIM * DIM, bufB, Wnbr + DIM * DIM, convb + DIM,
        gamma + DIM, beta + DIM, bnmean + DIM, bnvar + DIM,
        nullptr, bufC, DIM, DIM);
    // conv layer 2 (edge-weighted, no BN/ELU): bufC -> bufA
    agg_kernel<true><<<NN, 256, 0, stream>>>(bufC, srcArr, eattr, off, elist, bufB);
    gemm_kernel<EPI_BIAS, true><<<gg, 256, 0, stream>>>(
        bufC, Wself + 2 * DIM * DIM, bufB, Wnbr + 2 * DIM * DIM, convb + 2 * DIM,
        nullptr, nullptr, nullptr, nullptr, nullptr, bufA, DIM, DIM);

    // QKV projections from bufA
    gemm_kernel<EPI_BIAS, false><<<gg, 256, 0, stream>>>(
        bufA, Wqkv,                nullptr, nullptr, bqkv,
        nullptr, nullptr, nullptr, nullptr, nullptr, bufQ, DIM, DIM);
    gemm_kernel<EPI_BIAS, false><<<gg, 256, 0, stream>>>(
        bufA, Wqkv + DIM * DIM,    nullptr, nullptr, bqkv + DIM,
        nullptr, nullptr, nullptr, nullptr, nullptr, bufK, DIM, DIM);
    gemm_kernel<EPI_BIAS, false><<<gg, 256, 0, stream>>>(
        bufA, Wqkv + 2 * DIM * DIM, nullptr, nullptr, bqkv + 2 * DIM,
        nullptr, nullptr, nullptr, nullptr, nullptr, bufV, DIM, DIM);

    // flash attention -> bufC
    attn_kernel<<<dim3(NN / QB, NH), 256, 0, stream>>>(bufQ, bufK, bufV, bufC);

    // output projection + residual: bufB = bufA + bufC @ Wo + bo
    gemm_kernel<EPI_BIAS_RES, false><<<gg, 256, 0, stream>>>(
        bufC, Wo, nullptr, nullptr, bo,
        nullptr, nullptr, nullptr, nullptr, bufA, bufB, DIM, DIM);

    // fc1 + ELU: feats = elu(bufB @ fc1W + fc1b)
    gemm_kernel<EPI_BIAS_ELU, false><<<dim3(F1D / 64, NN / 64), 256, 0, stream>>>(
        bufB, fc1W, nullptr, nullptr, fc1b,
        nullptr, nullptr, nullptr, nullptr, nullptr, feats, DIM, F1D);

    // adapter routing -> out
    adapter_kernel<<<NN, 64, 0, stream>>>(feats, grp, AW1, Ab1, AW2, Ab2, outp);
}

// Round 2
// 684.503 us; speedup vs baseline: 1.0887x; 1.0887x over previous
//
#include <hip/hip_runtime.h>
#include <math.h>

#define NN   4096
#define DIM  256
#define NE   131072
#define NH   4
#define DH   64
#define F1D  128
#define NG   16
#define AD   32

enum { EPI_BIAS = 0, EPI_BNELU = 1, EPI_BIAS_ELU = 2, EPI_BIAS_RES = 3 };

// ---------------- CSR build ----------------
__global__ void csr_count(const int* __restrict__ dst, int* __restrict__ cnt) {
    int e = blockIdx.x * 256 + threadIdx.x;
    atomicAdd(&cnt[dst[e]], 1);
}

__global__ void csr_scan(const int* __restrict__ cnt, int* __restrict__ off) {
    int lane = threadIdx.x;             // 64 lanes, each owns 64 nodes
    int base = lane * (NN / 64);
    int s = 0;
    for (int i = 0; i < NN / 64; ++i) s += cnt[base + i];
    int acc = s;
    #pragma unroll
    for (int o = 1; o < 64; o <<= 1) {
        int t = __shfl_up(acc, o);
        if (lane >= o) acc += t;
    }
    int run = acc - s;                  // exclusive prefix
    for (int i = 0; i < NN / 64; ++i) { off[base + i] = run; run += cnt[base + i]; }
    if (lane == 63) off[NN] = run;
}

__global__ void csr_fill(const int* __restrict__ dst, const int* __restrict__ off,
                         int* __restrict__ cur, int* __restrict__ elist) {
    int e = blockIdx.x * 256 + threadIdx.x;
    int d = dst[e];
    int pos = off[d] + atomicAdd(&cur[d], 1);
    elist[pos] = e;
}

// ---------------- neighbor aggregation: one block per node ----------------
template<bool LAST>
__global__ __launch_bounds__(256) void agg_kernel(
    const float* __restrict__ x, const int* __restrict__ src,
    const float* __restrict__ eattr, const int* __restrict__ off,
    const int* __restrict__ elist, float* __restrict__ agg)
{
    int n = blockIdx.x;
    int d = threadIdx.x;
    int j0 = off[n], j1 = off[n + 1];
    float acc = 0.f;
    for (int j = j0; j < j1; ++j) {
        int e = elist[j];
        int s = src[e];
        float w = LAST ? eattr[e] : 1.f;
        acc = fmaf(x[(size_t)s * DIM + d], w, acc);
    }
    agg[(size_t)n * DIM + d] = acc;
}

// ---------------- fp32 tiled GEMM, 64x64 tile, BK=16, 4x4 microtile -------
template<int EPI, bool DUAL>
__global__ __launch_bounds__(256) void gemm_kernel(
    const float* __restrict__ A0, const float* __restrict__ B0,
    const float* __restrict__ A1, const float* __restrict__ B1,
    const float* __restrict__ bias,
    const float* __restrict__ gamma, const float* __restrict__ beta,
    const float* __restrict__ bnmean, const float* __restrict__ bnvar,
    const float* __restrict__ resid,
    float* __restrict__ out, int K, int M)
{
    __shared__ float As[16][68];
    __shared__ float Bs[16][64];

    const int tid  = threadIdx.x;
    const int row0 = blockIdx.y * 64;
    const int col0 = blockIdx.x * 64;
    const int ty = tid >> 4;
    const int tx = tid & 15;
    const int lrow = tid >> 2;
    const int lk4  = (tid & 3) * 4;
    const int bk   = tid >> 4;
    const int bc4  = (tid & 15) * 4;

    float acc[4][4] = {};
    const int kTot = DUAL ? 2 * K : K;
    for (int k0 = 0; k0 < kTot; k0 += 16) {
        const bool ph1 = DUAL && (k0 >= K);
        const float* A = ph1 ? A1 : A0;
        const float* B = ph1 ? B1 : B0;
        const int kb = ph1 ? (k0 - K) : k0;
        float4 av = *(const float4*)&A[(size_t)(row0 + lrow) * K + kb + lk4];
        float4 bv = *(const float4*)&B[(size_t)(kb + bk) * M + col0 + bc4];
        __syncthreads();
        As[lk4 + 0][lrow] = av.x;
        As[lk4 + 1][lrow] = av.y;
        As[lk4 + 2][lrow] = av.z;
        As[lk4 + 3][lrow] = av.w;
        *(float4*)&Bs[bk][bc4] = bv;
        __syncthreads();
        #pragma unroll
        for (int kk = 0; kk < 16; ++kk) {
            float4 a = *(const float4*)&As[kk][ty * 4];
            float4 b = *(const float4*)&Bs[kk][tx * 4];
            acc[0][0] = fmaf(a.x, b.x, acc[0][0]);
            acc[0][1] = fmaf(a.x, b.y, acc[0][1]);
            acc[0][2] = fmaf(a.x, b.z, acc[0][2]);
            acc[0][3] = fmaf(a.x, b.w, acc[0][3]);
            acc[1][0] = fmaf(a.y, b.x, acc[1][0]);
            acc[1][1] = fmaf(a.y, b.y, acc[1][1]);
            acc[1][2] = fmaf(a.y, b.z, acc[1][2]);
            acc[1][3] = fmaf(a.y, b.w, acc[1][3]);
            acc[2][0] = fmaf(a.z, b.x, acc[2][0]);
            acc[2][1] = fmaf(a.z, b.y, acc[2][1]);
            acc[2][2] = fmaf(a.z, b.z, acc[2][2]);
            acc[2][3] = fmaf(a.z, b.w, acc[2][3]);
            acc[3][0] = fmaf(a.w, b.x, acc[3][0]);
            acc[3][1] = fmaf(a.w, b.y, acc[3][1]);
            acc[3][2] = fmaf(a.w, b.z, acc[3][2]);
            acc[3][3] = fmaf(a.w, b.w, acc[3][3]);
        }
    }
    #pragma unroll
    for (int i = 0; i < 4; ++i) {
        const int r = row0 + ty * 4 + i;
        #pragma unroll
        for (int j = 0; j < 4; ++j) {
            const int c = col0 + tx * 4 + j;
            float v = acc[i][j] + bias[c];
            if (EPI == EPI_BNELU) {
                v = gamma[c] * (v - bnmean[c]) * rsqrtf(bnvar[c] + 1e-5f) + beta[c];
                v = v > 0.f ? v : expm1f(v);
            } else if (EPI == EPI_BIAS_ELU) {
                v = v > 0.f ? v : expm1f(v);
            } else if (EPI == EPI_BIAS_RES) {
                v += resid[(size_t)r * M + c];
            }
            out[(size_t)r * M + c] = v;
        }
    }
}

// ---------------- flash attention, fp32, split over keys ------------------
// grid (NN/QB, NH, NSPLIT), 256 threads, 4 blocks/CU co-resident.
// LDS: QsT 8K + KV union 17.4K + Ps 8.7K = 34.3KB.
// K and V are register-staged (loads issued under compute, written to the
// shared KV buffer after barriers) so one buffer serves both.
#define QB 32
#define KB 64
#define NSPLIT 2
#define KT_PER (NN / NSPLIT / KB)

__global__ __launch_bounds__(256, 4) void attn_kernel(
    const float* __restrict__ q, const float* __restrict__ k,
    const float* __restrict__ v,
    float* __restrict__ opart0, float* __restrict__ opart1,
    float* __restrict__ mpart, float* __restrict__ lpart)
{
    __shared__ float QsT[64][32];    // [d][qrow], q pre-scaled by 1/8
    __shared__ float KV[64][68];     // K phase: [d][krow]; V phase: [krow][d]
    __shared__ float Ps[QB][68];     // [qrow][krow] + state cols 64..66

    const int tid = threadIdx.x;
    const int h   = blockIdx.y;
    const int q0  = blockIdx.x * QB;
    const int sp  = blockIdx.z;
    const int kb0 = sp * (NN / NSPLIT);

    {   // load+transpose Q, row-per-lane (conflict-free), fold in 1/8
        const int qr = tid & 31, qseg = tid >> 5;   // qseg 0..7
        const float* qp = q + (size_t)(q0 + qr) * DIM + h * DH + qseg * 8;
        float4 a = ((const float4*)qp)[0];
        float4 b = ((const float4*)qp)[1];
        const int d0 = qseg * 8;
        QsT[d0 + 0][qr] = a.x * 0.125f; QsT[d0 + 1][qr] = a.y * 0.125f;
        QsT[d0 + 2][qr] = a.z * 0.125f; QsT[d0 + 3][qr] = a.w * 0.125f;
        QsT[d0 + 4][qr] = b.x * 0.125f; QsT[d0 + 5][qr] = b.y * 0.125f;
        QsT[d0 + 6][qr] = b.z * 0.125f; QsT[d0 + 7][qr] = b.w * 0.125f;
    }
    if (tid < QB) { Ps[tid][64] = -3.0e38f; Ps[tid][65] = 0.f; }

    const int kr = tid & 63, kseg = tid >> 6;       // loader: row-per-lane
    const int koff = h * DH + kseg * 16;
    float4 ka0, ka1, ka2, ka3;
    {   // issue K loads for tile 0 (land during first barrier)
        const float* kp = k + (size_t)(kb0 + kr) * DIM + koff;
        ka0 = ((const float4*)kp)[0]; ka1 = ((const float4*)kp)[1];
        ka2 = ((const float4*)kp)[2]; ka3 = ((const float4*)kp)[3];
    }

    float oacc[8] = {};
    const int pr = tid >> 3, pseg = tid & 7;        // PV mapping
    const int sy = tid >> 4, sx = tid & 15;         // S mapping

    __syncthreads();                                // Q + state ready
    for (int kt = 0; kt < KT_PER; ++kt) {
        {   // K regs -> LDS transposed: [d][krow]; 64 distinct kr/wave -> free
            const int c0 = kseg * 16;
            KV[c0 +  0][kr] = ka0.x; KV[c0 +  1][kr] = ka0.y;
            KV[c0 +  2][kr] = ka0.z; KV[c0 +  3][kr] = ka0.w;
            KV[c0 +  4][kr] = ka1.x; KV[c0 +  5][kr] = ka1.y;
            KV[c0 +  6][kr] = ka1.z; KV[c0 +  7][kr] = ka1.w;
            KV[c0 +  8][kr] = ka2.x; KV[c0 +  9][kr] = ka2.y;
            KV[c0 + 10][kr] = ka2.z; KV[c0 + 11][kr] = ka2.w;
            KV[c0 + 12][kr] = ka3.x; KV[c0 + 13][kr] = ka3.y;
            KV[c0 + 14][kr] = ka3.z; KV[c0 + 15][kr] = ka3.w;
        }
        // issue V loads for this tile (land during S phase)
        float4 va0, va1, va2, va3;
        {
            const float* vp = v + (size_t)(kb0 + kt * KB + kr) * DIM + koff;
            va0 = ((const float4*)vp)[0]; va1 = ((const float4*)vp)[1];
            va2 = ((const float4*)vp)[2]; va3 = ((const float4*)vp)[3];
        }
        __syncthreads();                            // K ready
        // ---- S = Q K^T (2 rows x 4 cols per thread) ----
        float sc[8] = {};
        #pragma unroll 8
        for (int d = 0; d < 64; ++d) {
            const float2 qd = *(const float2*)&QsT[d][sy * 2];
            const float4 kd = *(const float4*)&KV[d][sx * 4];
            sc[0] = fmaf(qd.x, kd.x, sc[0]);
            sc[1] = fmaf(qd.x, kd.y, sc[1]);
            sc[2] = fmaf(qd.x, kd.z, sc[2]);
            sc[3] = fmaf(qd.x, kd.w, sc[3]);
            sc[4] = fmaf(qd.y, kd.x, sc[4]);
            sc[5] = fmaf(qd.y, kd.y, sc[5]);
            sc[6] = fmaf(qd.y, kd.z, sc[6]);
            sc[7] = fmaf(qd.y, kd.w, sc[7]);
        }
        // ---- online softmax update (per row: 16 lanes, same wave) ----
        #pragma unroll
        for (int i = 0; i < 2; ++i) {
            const float* s4 = &sc[i * 4];
            float rm = fmaxf(fmaxf(s4[0], s4[1]), fmaxf(s4[2], s4[3]));
            #pragma unroll
            for (int mm = 1; mm < 16; mm <<= 1) rm = fmaxf(rm, __shfl_xor(rm, mm));
            const int r = sy * 2 + i;
            const float mold = Ps[r][64];
            const float mnew = fmaxf(mold, rm);
            const float p0 = __expf(s4[0] - mnew);
            const float p1 = __expf(s4[1] - mnew);
            const float p2 = __expf(s4[2] - mnew);
            const float p3 = __expf(s4[3] - mnew);
            float psum = (p0 + p1) + (p2 + p3);
            #pragma unroll
            for (int mm = 1; mm < 16; mm <<= 1) psum += __shfl_xor(psum, mm);
            *(float4*)&Ps[r][sx * 4] = make_float4(p0, p1, p2, p3);
            if (sx == 0) {
                const float fsc = __expf(mold - mnew);
                Ps[r][64] = mnew;
                Ps[r][65] = Ps[r][65] * fsc + psum;
                Ps[r][66] = fsc;
            }
        }
        __syncthreads();                            // Ps ready, K dead
        {   // V regs -> LDS: [krow][d]
            const int c0 = kseg * 16;
            *(float4*)&KV[kr][c0 +  0] = va0;
            *(float4*)&KV[kr][c0 +  4] = va1;
            *(float4*)&KV[kr][c0 +  8] = va2;
            *(float4*)&KV[kr][c0 + 12] = va3;
        }
        // issue K loads for next tile (land during PV phase)
        if (kt + 1 < KT_PER) {
            const float* kp = k + (size_t)(kb0 + (kt + 1) * KB + kr) * DIM + koff;
            ka0 = ((const float4*)kp)[0]; ka1 = ((const float4*)kp)[1];
            ka2 = ((const float4*)kp)[2]; ka3 = ((const float4*)kp)[3];
        }
        __syncthreads();                            // V ready
        // ---- PV accumulate (1 row x 8 dims per thread) ----
        const float fsc = Ps[pr][66];
        #pragma unroll
        for (int j = 0; j < 8; ++j) oacc[j] *= fsc;
        #pragma unroll 4
        for (int kk = 0; kk < 64; ++kk) {
            const float p = Ps[pr][kk];
            const float4 va = *(const float4*)&KV[kk][pseg * 8];
            const float4 vb = *(const float4*)&KV[kk][pseg * 8 + 4];
            oacc[0] = fmaf(p, va.x, oacc[0]);
            oacc[1] = fmaf(p, va.y, oacc[1]);
            oacc[2] = fmaf(p, va.z, oacc[2]);
            oacc[3] = fmaf(p, va.w, oacc[3]);
            oacc[4] = fmaf(p, vb.x, oacc[4]);
            oacc[5] = fmaf(p, vb.y, oacc[5]);
            oacc[6] = fmaf(p, vb.z, oacc[6]);
            oacc[7] = fmaf(p, vb.w, oacc[7]);
        }
        __syncthreads();                            // PV done, buffers free
    }
    // epilogue: unnormalized partial o + (m,l) per row
    float* ob = (sp == 0) ? opart0 : opart1;
    float* op = ob + (size_t)(q0 + pr) * DIM + h * DH + pseg * 8;
    ((float4*)op)[0] = make_float4(oacc[0], oacc[1], oacc[2], oacc[3]);
    ((float4*)op)[1] = make_float4(oacc[4], oacc[5], oacc[6], oacc[7]);
    if (pseg == 0) {
        mpart[sp * NN * NH + (q0 + pr) * NH + h] = Ps[pr][64];
        lpart[sp * NN * NH + (q0 + pr) * NH + h] = Ps[pr][65];
    }
}

// merge the NSPLIT partials: one float4 per thread
__global__ __launch_bounds__(256) void attn_combine(
    const float* __restrict__ o0, const float* __restrict__ o1,
    const float* __restrict__ mpart, const float* __restrict__ lpart,
    float* __restrict__ out)
{
    const int gid = blockIdx.x * 256 + threadIdx.x;
    const int row = gid >> 6;
    const int c4  = (gid & 63) * 4;
    const int h   = c4 >> 6;
    const float m0 = mpart[row * NH + h];
    const float m1 = mpart[NN * NH + row * NH + h];
    const float M  = fmaxf(m0, m1);
    const float w0 = __expf(m0 - M), w1 = __expf(m1 - M);
    const float inv = 1.f /
        (lpart[row * NH + h] * w0 + lpart[NN * NH + row * NH + h] * w1);
    const float4 a = *(const float4*)&o0[(size_t)row * DIM + c4];
    const float4 b = *(const float4*)&o1[(size_t)row * DIM + c4];
    float4 r;
    r.x = (a.x * w0 + b.x * w1) * inv;
    r.y = (a.y * w0 + b.y * w1) * inv;
    r.z = (a.z * w0 + b.z * w1) * inv;
    r.w = (a.w * w0 + b.w * w1) * inv;
    *(float4*)&out[(size_t)row * DIM + c4] = r;
}

// ---------------- per-node group adapter: 1 wave per node -----------------
__global__ __launch_bounds__(64) void adapter_kernel(
    const float* __restrict__ feats, const int* __restrict__ grp,
    const float* __restrict__ AW1, const float* __restrict__ Ab1,
    const float* __restrict__ AW2, const float* __restrict__ Ab2,
    float* __restrict__ out)
{
    const int n = blockIdx.x;
    const int lane = threadIdx.x;
    __shared__ float f[F1D];
    f[lane]      = feats[(size_t)n * F1D + lane];
    f[lane + 64] = feats[(size_t)n * F1D + 64 + lane];
    __syncthreads();
    const int g = grp[n];
    const float* W1 = AW1 + (size_t)g * F1D * AD;
    const int a = lane & 31;
    const int half = lane >> 5;
    float hsum = 0.f;
    for (int d = 0; d < 64; ++d)
        hsum = fmaf(f[half * 64 + d], W1[(half * 64 + d) * AD + a], hsum);
    hsum += __shfl_xor(hsum, 32);
    hsum = fmaxf(hsum + Ab1[g * AD + a], 0.f);
    float p = hsum * AW2[g * AD + a];
    #pragma unroll
    for (int mm = 1; mm < 32; mm <<= 1) p += __shfl_xor(p, mm);
    if (lane == 0) out[n] = p + Ab2[g];
}

// ---------------- host-side orchestration ----------------
extern "C" void kernel_launch(void* const* d_in, const int* in_sizes, int n_in,
                              void* d_out, int out_size, void* d_ws, size_t ws_size,
                              hipStream_t stream)
{
    const float* x_in   = (const float*)d_in[0];
    const float* eattr  = (const float*)d_in[1];
    const float* Wself  = (const float*)d_in[2];
    const float* Wnbr   = (const float*)d_in[3];
    const float* convb  = (const float*)d_in[4];
    const float* gamma  = (const float*)d_in[5];
    const float* beta   = (const float*)d_in[6];
    const float* bnmean = (const float*)d_in[7];
    const float* bnvar  = (const float*)d_in[8];
    const float* Wqkv   = (const float*)d_in[9];
    const float* bqkv   = (const float*)d_in[10];
    const float* Wo     = (const float*)d_in[11];
    const float* bo     = (const float*)d_in[12];
    const float* fc1W   = (const float*)d_in[13];
    const float* fc1b   = (const float*)d_in[14];
    const float* AW1    = (const float*)d_in[15];
    const float* Ab1    = (const float*)d_in[16];
    const float* AW2    = (const float*)d_in[17];
    const float* Ab2    = (const float*)d_in[18];
    const int*   eidx   = (const int*)d_in[19];
    const int*   grp    = (const int*)d_in[20];
    const int* srcArr = eidx;
    const int* dstArr = eidx + NE;

    float* fws = (float*)d_ws;
    const size_t NM = (size_t)NN * DIM;
    float* bufA   = fws;            // x after layer0 / layer2
    float* bufB   = fws + NM;       // agg scratch; attn opart0; post-residual x
    float* bufC   = fws + 2 * NM;   // x after layer1; attention o
    float* bufQ   = fws + 3 * NM;
    float* bufK   = fws + 4 * NM;
    float* bufV   = fws + 5 * NM;
    float* opart1 = fws + 6 * NM;
    float* feats  = fws + 7 * NM;   // NN x F1D  (= NM/2)
    float* mlbuf  = fws + 7 * NM + NM / 2;   // mpart[2][NN][NH] + lpart[...]
    float* mpart  = mlbuf;
    float* lpart  = mlbuf + 2 * NN * NH;
    int* iws   = (int*)(mlbuf + 4 * NN * NH);
    int* off   = iws;                    // NN+1
    int* cur   = iws + NN + 1;           // NN
    int* elist = iws + 2 * NN + 1;       // NE
    float* outp = (float*)d_out;

    // CSR build
    hipMemsetAsync(cur, 0, NN * sizeof(int), stream);
    csr_count<<<NE / 256, 256, 0, stream>>>(dstArr, cur);
    csr_scan<<<1, 64, 0, stream>>>(cur, off);
    hipMemsetAsync(cur, 0, NN * sizeof(int), stream);
    csr_fill<<<NE / 256, 256, 0, stream>>>(dstArr, off, cur, elist);

    const dim3 gg(DIM / 64, NN / 64);

    // conv layer 0: x_in -> bufA
    agg_kernel<false><<<NN, 256, 0, stream>>>(x_in, srcArr, eattr, off, elist, bufB);
    gemm_kernel<EPI_BNELU, true><<<gg, 256, 0, stream>>>(
        x_in, Wself, bufB, Wnbr, convb, gamma, beta, bnmean, bnvar,
        nullptr, bufA, DIM, DIM);
    // conv layer 1: bufA -> bufC
    agg_kernel<false><<<NN, 256, 0, stream>>>(bufA, srcArr, eattr, off, elist, bufB);
    gemm_kernel<EPI_BNELU, true><<<gg, 256, 0, stream>>>(
        bufA, Wself + DIM * DIM, bufB, Wnbr + DIM * DIM, convb + DIM,
        gamma + DIM, beta + DIM, bnmean + DIM, bnvar + DIM,
        nullptr, bufC, DIM, DIM);
    // conv layer 2 (edge-weighted, no BN/ELU): bufC -> bufA
    agg_kernel<true><<<NN, 256, 0, stream>>>(bufC, srcArr, eattr, off, elist, bufB);
    gemm_kernel<EPI_BIAS, true><<<gg, 256, 0, stream>>>(
        bufC, Wself + 2 * DIM * DIM, bufB, Wnbr + 2 * DIM * DIM, convb + 2 * DIM,
        nullptr, nullptr, nullptr, nullptr, nullptr, bufA, DIM, DIM);

    // QKV projections from bufA
    gemm_kernel<EPI_BIAS, false><<<gg, 256, 0, stream>>>(
        bufA, Wqkv,                nullptr, nullptr, bqkv,
        nullptr, nullptr, nullptr, nullptr, nullptr, bufQ, DIM, DIM);
    gemm_kernel<EPI_BIAS, false><<<gg, 256, 0, stream>>>(
        bufA, Wqkv + DIM * DIM,    nullptr, nullptr, bqkv + DIM,
        nullptr, nullptr, nullptr, nullptr, nullptr, bufK, DIM, DIM);
    gemm_kernel<EPI_BIAS, false><<<gg, 256, 0, stream>>>(
        bufA, Wqkv + 2 * DIM * DIM, nullptr, nullptr, bqkv + 2 * DIM,
        nullptr, nullptr, nullptr, nullptr, nullptr, bufV, DIM, DIM);

    // flash attention (split over keys) -> partials, then combine -> bufC
    attn_kernel<<<dim3(NN / QB, NH, NSPLIT), 256, 0, stream>>>(
        bufQ, bufK, bufV, bufB, opart1, mpart, lpart);
    attn_combine<<<NN * DIM / 4 / 256, 256, 0, stream>>>(
        bufB, opart1, mpart, lpart, bufC);

    // output projection + residual: bufB = bufA + bufC @ Wo + bo
    gemm_kernel<EPI_BIAS_RES, false><<<gg, 256, 0, stream>>>(
        bufC, Wo, nullptr, nullptr, bo,
        nullptr, nullptr, nullptr, nullptr, bufA, bufB, DIM, DIM);

    // fc1 + ELU: feats = elu(bufB @ fc1W + fc1b)
    gemm_kernel<EPI_BIAS_ELU, false><<<dim3(F1D / 64, NN / 64), 256, 0, stream>>>(
        bufB, fc1W, nullptr, nullptr, fc1b,
        nullptr, nullptr, nullptr, nullptr, nullptr, feats, DIM, F1D);

    // adapter routing -> out
    adapter_kernel<<<NN, 64, 0, stream>>>(feats, grp, AW1, Ab1, AW2, Ab2, outp);
}

// Round 3
// 609.806 us; speedup vs baseline: 1.2220x; 1.1225x over previous
//
#include <hip/hip_runtime.h>
#include <math.h>

#define NN   4096
#define DIM  256
#define NE   131072
#define NH   4
#define DH   64
#define F1D  128
#define NG   16
#define AD   32

enum { EPI_BIAS = 0, EPI_BNELU = 1, EPI_BIAS_ELU = 2, EPI_BIAS_RES = 3 };

// ---------------- CSR build ----------------
__global__ void csr_count(const int* __restrict__ dst, int* __restrict__ cnt) {
    int e = blockIdx.x * 256 + threadIdx.x;
    atomicAdd(&cnt[dst[e]], 1);
}

__global__ void csr_scan(const int* __restrict__ cnt, int* __restrict__ off) {
    int lane = threadIdx.x;             // 64 lanes, each owns 64 nodes
    int base = lane * (NN / 64);
    int s = 0;
    for (int i = 0; i < NN / 64; ++i) s += cnt[base + i];
    int acc = s;
    #pragma unroll
    for (int o = 1; o < 64; o <<= 1) {
        int t = __shfl_up(acc, o);
        if (lane >= o) acc += t;
    }
    int run = acc - s;                  // exclusive prefix
    for (int i = 0; i < NN / 64; ++i) { off[base + i] = run; run += cnt[base + i]; }
    if (lane == 63) off[NN] = run;
}

__global__ void csr_fill(const int* __restrict__ dst, const int* __restrict__ off,
                         int* __restrict__ cur, int* __restrict__ elist) {
    int e = blockIdx.x * 256 + threadIdx.x;
    int d = dst[e];
    int pos = off[d] + atomicAdd(&cur[d], 1);
    elist[pos] = e;
}

// ---------------- neighbor aggregation: one block per node ----------------
template<bool LAST>
__global__ __launch_bounds__(256) void agg_kernel(
    const float* __restrict__ x, const int* __restrict__ src,
    const float* __restrict__ eattr, const int* __restrict__ off,
    const int* __restrict__ elist, float* __restrict__ agg)
{
    int n = blockIdx.x;
    int d = threadIdx.x;
    int j0 = off[n], j1 = off[n + 1];
    float acc = 0.f;
    for (int j = j0; j < j1; ++j) {
        int e = elist[j];
        int s = src[e];
        float w = LAST ? eattr[e] : 1.f;
        acc = fmaf(x[(size_t)s * DIM + d], w, acc);
    }
    agg[(size_t)n * DIM + d] = acc;
}

// ---------------- fp32 tiled GEMM, 64x64 tile, BK=16, 4x4 microtile -------
// QKV mode: B0 = 3 stacked KxM matrices, out = 3 stacked NxM outputs,
// bias = 3 stacked M-vectors; grid.x spans 3*M/64 col-blocks.
template<int EPI, bool DUAL, bool QKV = false>
__global__ __launch_bounds__(256) void gemm_kernel(
    const float* __restrict__ A0, const float* __restrict__ B0,
    const float* __restrict__ A1, const float* __restrict__ B1,
    const float* __restrict__ bias,
    const float* __restrict__ gamma, const float* __restrict__ beta,
    const float* __restrict__ bnmean, const float* __restrict__ bnvar,
    const float* __restrict__ resid,
    float* __restrict__ out, int K, int M)
{
    __shared__ float As[16][68];
    __shared__ float Bs[16][64];

    const int tid  = threadIdx.x;
    const int row0 = blockIdx.y * 64;
    const int c0raw = blockIdx.x * 64;
    const int mat  = QKV ? (c0raw >> 8) : 0;
    const int col0 = QKV ? (c0raw & 255) : c0raw;
    const float* Bp = QKV ? B0 + (size_t)mat * K * M : B0;
    const float* biasp = QKV ? bias + mat * M : bias;
    float* outp = QKV ? out + (size_t)mat * NN * M : out;

    const int ty = tid >> 4;
    const int tx = tid & 15;
    const int lrow = tid >> 2;
    const int lk4  = (tid & 3) * 4;
    const int bk   = tid >> 4;
    const int bc4  = (tid & 15) * 4;

    float acc[4][4] = {};
    const int kTot = DUAL ? 2 * K : K;
    for (int k0 = 0; k0 < kTot; k0 += 16) {
        const bool ph1 = DUAL && (k0 >= K);
        const float* A = ph1 ? A1 : A0;
        const float* B = ph1 ? B1 : Bp;
        const int kb = ph1 ? (k0 - K) : k0;
        float4 av = *(const float4*)&A[(size_t)(row0 + lrow) * K + kb + lk4];
        float4 bv = *(const float4*)&B[(size_t)(kb + bk) * M + col0 + bc4];
        __syncthreads();
        As[lk4 + 0][lrow] = av.x;
        As[lk4 + 1][lrow] = av.y;
        As[lk4 + 2][lrow] = av.z;
        As[lk4 + 3][lrow] = av.w;
        *(float4*)&Bs[bk][bc4] = bv;
        __syncthreads();
        #pragma unroll
        for (int kk = 0; kk < 16; ++kk) {
            float4 a = *(const float4*)&As[kk][ty * 4];
            float4 b = *(const float4*)&Bs[kk][tx * 4];
            acc[0][0] = fmaf(a.x, b.x, acc[0][0]);
            acc[0][1] = fmaf(a.x, b.y, acc[0][1]);
            acc[0][2] = fmaf(a.x, b.z, acc[0][2]);
            acc[0][3] = fmaf(a.x, b.w, acc[0][3]);
            acc[1][0] = fmaf(a.y, b.x, acc[1][0]);
            acc[1][1] = fmaf(a.y, b.y, acc[1][1]);
            acc[1][2] = fmaf(a.y, b.z, acc[1][2]);
            acc[1][3] = fmaf(a.y, b.w, acc[1][3]);
            acc[2][0] = fmaf(a.z, b.x, acc[2][0]);
            acc[2][1] = fmaf(a.z, b.y, acc[2][1]);
            acc[2][2] = fmaf(a.z, b.z, acc[2][2]);
            acc[2][3] = fmaf(a.z, b.w, acc[2][3]);
            acc[3][0] = fmaf(a.w, b.x, acc[3][0]);
            acc[3][1] = fmaf(a.w, b.y, acc[3][1]);
            acc[3][2] = fmaf(a.w, b.z, acc[3][2]);
            acc[3][3] = fmaf(a.w, b.w, acc[3][3]);
        }
    }
    #pragma unroll
    for (int i = 0; i < 4; ++i) {
        const int r = row0 + ty * 4 + i;
        #pragma unroll
        for (int j = 0; j < 4; ++j) {
            const int c = col0 + tx * 4 + j;
            float v = acc[i][j] + biasp[c];
            if (EPI == EPI_BNELU) {
                v = gamma[c] * (v - bnmean[c]) * rsqrtf(bnvar[c] + 1e-5f) + beta[c];
                v = v > 0.f ? v : expm1f(v);
            } else if (EPI == EPI_BIAS_ELU) {
                v = v > 0.f ? v : expm1f(v);
            } else if (EPI == EPI_BIAS_RES) {
                v += resid[(size_t)r * M + c];
            }
            outp[(size_t)r * M + c] = v;
        }
    }
}

// ---------------- flash attention, fp32, 64x64 tiles, 4x4 microtiles ------
// grid (NN/QB, NH, NSPLIT) = (64,4,3) = 768 blocks = 3/CU. LDS 50.8KB.
// S held in registers; P stored transposed PsT[k][q] for vectorized PV.
#define QB 64
#define KB 64
#define NSPLIT 3
#define NKT (NN / KB)

__global__ __launch_bounds__(256, 3) void attn_kernel(
    const float* __restrict__ q, const float* __restrict__ k,
    const float* __restrict__ v,
    float* __restrict__ op0, float* __restrict__ op1, float* __restrict__ op2,
    float* __restrict__ mpart, float* __restrict__ lpart)
{
    __shared__ float QsT[64][64];    // [d][qrow], scaled by 1/8
    __shared__ float KVT[64][68];    // [d][krow]: K phase and V phase (both transposed)
    __shared__ float PsT[64][68];    // [k][qrow]
    __shared__ float mrow[QB], lrow[QB], frow[QB];

    const int tid = threadIdx.x;
    const int h   = blockIdx.y;
    const int q0  = blockIdx.x * QB;
    const int sp  = blockIdx.z;
    const int kt0 = (sp * NKT) / NSPLIT;
    const int kt1 = ((sp + 1) * NKT) / NSPLIT;

    const int lr  = tid & 63;       // loader: row
    const int ld0 = (tid >> 6) * 16;// loader: dim-quarter base
    const int gco = h * DH + ld0;

    {   // Q -> QsT transposed (scatter stores: consecutive lr -> 2-way, free)
        const float* qp = q + (size_t)(q0 + lr) * DIM + gco;
        float4 a = ((const float4*)qp)[0];
        float4 b = ((const float4*)qp)[1];
        float4 c = ((const float4*)qp)[2];
        float4 d = ((const float4*)qp)[3];
        QsT[ld0+ 0][lr]=a.x*0.125f; QsT[ld0+ 1][lr]=a.y*0.125f;
        QsT[ld0+ 2][lr]=a.z*0.125f; QsT[ld0+ 3][lr]=a.w*0.125f;
        QsT[ld0+ 4][lr]=b.x*0.125f; QsT[ld0+ 5][lr]=b.y*0.125f;
        QsT[ld0+ 6][lr]=b.z*0.125f; QsT[ld0+ 7][lr]=b.w*0.125f;
        QsT[ld0+ 8][lr]=c.x*0.125f; QsT[ld0+ 9][lr]=c.y*0.125f;
        QsT[ld0+10][lr]=c.z*0.125f; QsT[ld0+11][lr]=c.w*0.125f;
        QsT[ld0+12][lr]=d.x*0.125f; QsT[ld0+13][lr]=d.y*0.125f;
        QsT[ld0+14][lr]=d.z*0.125f; QsT[ld0+15][lr]=d.w*0.125f;
    }
    if (tid < QB) { mrow[tid] = -3.0e38f; lrow[tid] = 0.f; }

    float4 ka0, ka1, ka2, ka3;
    {   // prefetch first K tile
        const float* kp = k + (size_t)(kt0 * KB + lr) * DIM + gco;
        ka0 = ((const float4*)kp)[0]; ka1 = ((const float4*)kp)[1];
        ka2 = ((const float4*)kp)[2]; ka3 = ((const float4*)kp)[3];
    }

    const int sy = tid >> 4, sx = tid & 15;     // S / softmax mapping
    const int pq = tid & 15, pd = tid >> 4;     // PV mapping

    float oacc[4][4] = {};
    __syncthreads();                            // Q + state ready
    for (int kt = kt0; kt < kt1; ++kt) {
        {   // K regs -> KVT transposed
            KVT[ld0+ 0][lr]=ka0.x; KVT[ld0+ 1][lr]=ka0.y;
            KVT[ld0+ 2][lr]=ka0.z; KVT[ld0+ 3][lr]=ka0.w;
            KVT[ld0+ 4][lr]=ka1.x; KVT[ld0+ 5][lr]=ka1.y;
            KVT[ld0+ 6][lr]=ka1.z; KVT[ld0+ 7][lr]=ka1.w;
            KVT[ld0+ 8][lr]=ka2.x; KVT[ld0+ 9][lr]=ka2.y;
            KVT[ld0+10][lr]=ka2.z; KVT[ld0+11][lr]=ka2.w;
            KVT[ld0+12][lr]=ka3.x; KVT[ld0+13][lr]=ka3.y;
            KVT[ld0+14][lr]=ka3.z; KVT[ld0+15][lr]=ka3.w;
        }
        float4 va0, va1, va2, va3;
        {   // issue V loads (land during S phase)
            const float* vp = v + (size_t)(kt * KB + lr) * DIM + gco;
            va0 = ((const float4*)vp)[0]; va1 = ((const float4*)vp)[1];
            va2 = ((const float4*)vp)[2]; va3 = ((const float4*)vp)[3];
        }
        __syncthreads();                        // B1: K ready
        // ---- S = Q K^T : 4x4 per thread, Q read is broadcast ----
        float sc[4][4] = {};
        #pragma unroll 8
        for (int d = 0; d < 64; ++d) {
            const float4 qv = *(const float4*)&QsT[d][sy * 4];
            const float4 kv = *(const float4*)&KVT[d][sx * 4];
            sc[0][0]=fmaf(qv.x,kv.x,sc[0][0]); sc[0][1]=fmaf(qv.x,kv.y,sc[0][1]);
            sc[0][2]=fmaf(qv.x,kv.z,sc[0][2]); sc[0][3]=fmaf(qv.x,kv.w,sc[0][3]);
            sc[1][0]=fmaf(qv.y,kv.x,sc[1][0]); sc[1][1]=fmaf(qv.y,kv.y,sc[1][1]);
            sc[1][2]=fmaf(qv.y,kv.z,sc[1][2]); sc[1][3]=fmaf(qv.y,kv.w,sc[1][3]);
            sc[2][0]=fmaf(qv.z,kv.x,sc[2][0]); sc[2][1]=fmaf(qv.z,kv.y,sc[2][1]);
            sc[2][2]=fmaf(qv.z,kv.z,sc[2][2]); sc[2][3]=fmaf(qv.z,kv.w,sc[2][3]);
            sc[3][0]=fmaf(qv.w,kv.x,sc[3][0]); sc[3][1]=fmaf(qv.w,kv.y,sc[3][1]);
            sc[3][2]=fmaf(qv.w,kv.z,sc[3][2]); sc[3][3]=fmaf(qv.w,kv.w,sc[3][3]);
        }
        // ---- online softmax: rows 4sy..4sy+3, 16 lanes (sx) per row ----
        float p[4][4];
        #pragma unroll
        for (int i = 0; i < 4; ++i) {
            float rm = fmaxf(fmaxf(sc[i][0], sc[i][1]), fmaxf(sc[i][2], sc[i][3]));
            #pragma unroll
            for (int mm = 1; mm < 16; mm <<= 1) rm = fmaxf(rm, __shfl_xor(rm, mm));
            const int r = sy * 4 + i;
            const float mold = mrow[r];
            const float mnew = fmaxf(mold, rm);
            p[i][0] = __expf(sc[i][0] - mnew);
            p[i][1] = __expf(sc[i][1] - mnew);
            p[i][2] = __expf(sc[i][2] - mnew);
            p[i][3] = __expf(sc[i][3] - mnew);
            float ps = (p[i][0] + p[i][1]) + (p[i][2] + p[i][3]);
            #pragma unroll
            for (int mm = 1; mm < 16; mm <<= 1) ps += __shfl_xor(ps, mm);
            if (sx == 0) {
                const float f = __expf(mold - mnew);
                mrow[r] = mnew;
                lrow[r] = lrow[r] * f + ps;
                frow[r] = f;
            }
        }
        #pragma unroll
        for (int j = 0; j < 4; ++j)
            *(float4*)&PsT[sx * 4 + j][sy * 4] =
                make_float4(p[0][j], p[1][j], p[2][j], p[3][j]);
        __syncthreads();                        // B2: PsT+state ready, K dead
        {   // V regs -> KVT transposed
            KVT[ld0+ 0][lr]=va0.x; KVT[ld0+ 1][lr]=va0.y;
            KVT[ld0+ 2][lr]=va0.z; KVT[ld0+ 3][lr]=va0.w;
            KVT[ld0+ 4][lr]=va1.x; KVT[ld0+ 5][lr]=va1.y;
            KVT[ld0+ 6][lr]=va1.z; KVT[ld0+ 7][lr]=va1.w;
            KVT[ld0+ 8][lr]=va2.x; KVT[ld0+ 9][lr]=va2.y;
            KVT[ld0+10][lr]=va2.z; KVT[ld0+11][lr]=va2.w;
            KVT[ld0+12][lr]=va3.x; KVT[ld0+13][lr]=va3.y;
            KVT[ld0+14][lr]=va3.z; KVT[ld0+15][lr]=va3.w;
        }
        if (kt + 1 < kt1) {     // prefetch next K (lands during PV)
            const float* kp = k + (size_t)((kt + 1) * KB + lr) * DIM + gco;
            ka0 = ((const float4*)kp)[0]; ka1 = ((const float4*)kp)[1];
            ka2 = ((const float4*)kp)[2]; ka3 = ((const float4*)kp)[3];
        }
        __syncthreads();                        // B3: V ready
        // ---- PV: O[4q][4d] per thread; P read float4, V broadcast ----
        {
            const float f0 = frow[pq * 4 + 0];
            const float f1 = frow[pq * 4 + 1];
            const float f2 = frow[pq * 4 + 2];
            const float f3 = frow[pq * 4 + 3];
            #pragma unroll
            for (int m = 0; m < 4; ++m) {
                oacc[0][m] *= f0; oacc[1][m] *= f1;
                oacc[2][m] *= f2; oacc[3][m] *= f3;
            }
        }
        #pragma unroll 4
        for (int kk = 0; kk < 64; ++kk) {
            const float4 pv = *(const float4*)&PsT[kk][pq * 4];
            const float v0 = KVT[pd * 4 + 0][kk];
            const float v1 = KVT[pd * 4 + 1][kk];
            const float v2 = KVT[pd * 4 + 2][kk];
            const float v3 = KVT[pd * 4 + 3][kk];
            oacc[0][0]=fmaf(pv.x,v0,oacc[0][0]); oacc[0][1]=fmaf(pv.x,v1,oacc[0][1]);
            oacc[0][2]=fmaf(pv.x,v2,oacc[0][2]); oacc[0][3]=fmaf(pv.x,v3,oacc[0][3]);
            oacc[1][0]=fmaf(pv.y,v0,oacc[1][0]); oacc[1][1]=fmaf(pv.y,v1,oacc[1][1]);
            oacc[1][2]=fmaf(pv.y,v2,oacc[1][2]); oacc[1][3]=fmaf(pv.y,v3,oacc[1][3]);
            oacc[2][0]=fmaf(pv.z,v0,oacc[2][0]); oacc[2][1]=fmaf(pv.z,v1,oacc[2][1]);
            oacc[2][2]=fmaf(pv.z,v2,oacc[2][2]); oacc[2][3]=fmaf(pv.z,v3,oacc[2][3]);
            oacc[3][0]=fmaf(pv.w,v0,oacc[3][0]); oacc[3][1]=fmaf(pv.w,v1,oacc[3][1]);
            oacc[3][2]=fmaf(pv.w,v2,oacc[3][2]); oacc[3][3]=fmaf(pv.w,v3,oacc[3][3]);
        }
        __syncthreads();                        // B4: PV done, buffers free
    }
    // epilogue: unnormalized partial + (m,l)
    float* ob = (sp == 0) ? op0 : ((sp == 1) ? op1 : op2);
    #pragma unroll
    for (int i = 0; i < 4; ++i) {
        const int r = q0 + pq * 4 + i;
        *(float4*)&ob[(size_t)r * DIM + h * DH + pd * 4] =
            make_float4(oacc[i][0], oacc[i][1], oacc[i][2], oacc[i][3]);
    }
    if (pd == 0) {
        #pragma unroll
        for (int i = 0; i < 4; ++i) {
            const int r = pq * 4 + i;
            mpart[((size_t)sp * NN + q0 + r) * NH + h] = mrow[r];
            lpart[((size_t)sp * NN + q0 + r) * NH + h] = lrow[r];
        }
    }
}

// merge the NSPLIT partials: one float4 per thread
__global__ __launch_bounds__(256) void attn_combine(
    const float* __restrict__ o0, const float* __restrict__ o1,
    const float* __restrict__ o2,
    const float* __restrict__ mp, const float* __restrict__ lp,
    float* __restrict__ out)
{
    const int gid = blockIdx.x * 256 + threadIdx.x;
    const int row = gid >> 6;
    const int c4  = (gid & 63) * 4;
    const int h   = c4 >> 6;
    const float m0 = mp[row * NH + h];
    const float m1 = mp[(NN + row) * NH + h];
    const float m2 = mp[(2 * NN + row) * NH + h];
    const float M  = fmaxf(fmaxf(m0, m1), m2);
    const float w0 = __expf(m0 - M), w1 = __expf(m1 - M), w2 = __expf(m2 - M);
    const float inv = 1.f / (lp[row * NH + h] * w0 +
                             lp[(NN + row) * NH + h] * w1 +
                             lp[(2 * NN + row) * NH + h] * w2);
    const float4 a = *(const float4*)&o0[(size_t)row * DIM + c4];
    const float4 b = *(const float4*)&o1[(size_t)row * DIM + c4];
    const float4 c = *(const float4*)&o2[(size_t)row * DIM + c4];
    float4 r;
    r.x = (a.x * w0 + b.x * w1 + c.x * w2) * inv;
    r.y = (a.y * w0 + b.y * w1 + c.y * w2) * inv;
    r.z = (a.z * w0 + b.z * w1 + c.z * w2) * inv;
    r.w = (a.w * w0 + b.w * w1 + c.w * w2) * inv;
    *(float4*)&out[(size_t)row * DIM + c4] = r;
}

// ---------------- per-node group adapter: 1 wave per node -----------------
__global__ __launch_bounds__(64) void adapter_kernel(
    const float* __restrict__ feats, const int* __restrict__ grp,
    const float* __restrict__ AW1, const float* __restrict__ Ab1,
    const float* __restrict__ AW2, const float* __restrict__ Ab2,
    float* __restrict__ out)
{
    const int n = blockIdx.x;
    const int lane = threadIdx.x;
    __shared__ float f[F1D];
    f[lane]      = feats[(size_t)n * F1D + lane];
    f[lane + 64] = feats[(size_t)n * F1D + 64 + lane];
    __syncthreads();
    const int g = grp[n];
    const float* W1 = AW1 + (size_t)g * F1D * AD;
    const int a = lane & 31;
    const int half = lane >> 5;
    float hsum = 0.f;
    for (int d = 0; d < 64; ++d)
        hsum = fmaf(f[half * 64 + d], W1[(half * 64 + d) * AD + a], hsum);
    hsum += __shfl_xor(hsum, 32);
    hsum = fmaxf(hsum + Ab1[g * AD + a], 0.f);
    float p = hsum * AW2[g * AD + a];
    #pragma unroll
    for (int mm = 1; mm < 32; mm <<= 1) p += __shfl_xor(p, mm);
    if (lane == 0) out[n] = p + Ab2[g];
}

// ---------------- host-side orchestration ----------------
extern "C" void kernel_launch(void* const* d_in, const int* in_sizes, int n_in,
                              void* d_out, int out_size, void* d_ws, size_t ws_size,
                              hipStream_t stream)
{
    const float* x_in   = (const float*)d_in[0];
    const float* eattr  = (const float*)d_in[1];
    const float* Wself  = (const float*)d_in[2];
    const float* Wnbr   = (const float*)d_in[3];
    const float* convb  = (const float*)d_in[4];
    const float* gamma  = (const float*)d_in[5];
    const float* beta   = (const float*)d_in[6];
    const float* bnmean = (const float*)d_in[7];
    const float* bnvar  = (const float*)d_in[8];
    const float* Wqkv   = (const float*)d_in[9];
    const float* bqkv   = (const float*)d_in[10];
    const float* Wo     = (const float*)d_in[11];
    const float* bo     = (const float*)d_in[12];
    const float* fc1W   = (const float*)d_in[13];
    const float* fc1b   = (const float*)d_in[14];
    const float* AW1    = (const float*)d_in[15];
    const float* Ab1    = (const float*)d_in[16];
    const float* AW2    = (const float*)d_in[17];
    const float* Ab2    = (const float*)d_in[18];
    const int*   eidx   = (const int*)d_in[19];
    const int*   grp    = (const int*)d_in[20];
    const int* srcArr = eidx;
    const int* dstArr = eidx + NE;

    float* fws = (float*)d_ws;
    const size_t NM = (size_t)NN * DIM;
    float* bufA   = fws;            // x after layer0 / layer2
    float* bufB   = fws + NM;       // agg scratch; attn opart0; post-residual x
    float* bufC   = fws + 2 * NM;   // x after layer1; attn opart1
    float* bufQ   = fws + 3 * NM;   // Q; later combined attention o
    float* bufK   = fws + 4 * NM;
    float* bufV   = fws + 5 * NM;
    float* opart2 = fws + 6 * NM;
    float* feats  = fws + 7 * NM;   // NN x F1D
    float* mlbuf  = fws + 7 * NM + NM / 2;
    float* mpart  = mlbuf;                       // [3][NN][NH]
    float* lpart  = mlbuf + 3 * NN * NH;         // [3][NN][NH]
    int* iws   = (int*)(mlbuf + 6 * NN * NH);
    int* off   = iws;                    // NN+1
    int* cur   = iws + NN + 1;           // NN
    int* elist = iws + 2 * NN + 1;       // NE
    float* outp = (float*)d_out;

    // CSR build
    hipMemsetAsync(cur, 0, NN * sizeof(int), stream);
    csr_count<<<NE / 256, 256, 0, stream>>>(dstArr, cur);
    csr_scan<<<1, 64, 0, stream>>>(cur, off);
    hipMemsetAsync(cur, 0, NN * sizeof(int), stream);
    csr_fill<<<NE / 256, 256, 0, stream>>>(dstArr, off, cur, elist);

    const dim3 gg(DIM / 64, NN / 64);

    // conv layer 0: x_in -> bufA
    agg_kernel<false><<<NN, 256, 0, stream>>>(x_in, srcArr, eattr, off, elist, bufB);
    gemm_kernel<EPI_BNELU, true><<<gg, 256, 0, stream>>>(
        x_in, Wself, bufB, Wnbr, convb, gamma, beta, bnmean, bnvar,
        nullptr, bufA, DIM, DIM);
    // conv layer 1: bufA -> bufC
    agg_kernel<false><<<NN, 256, 0, stream>>>(bufA, srcArr, eattr, off, elist, bufB);
    gemm_kernel<EPI_BNELU, true><<<gg, 256, 0, stream>>>(
        bufA, Wself + DIM * DIM, bufB, Wnbr + DIM * DIM, convb + DIM,
        gamma + DIM, beta + DIM, bnmean + DIM, bnvar + DIM,
        nullptr, bufC, DIM, DIM);
    // conv layer 2 (edge-weighted, no BN/ELU): bufC -> bufA
    agg_kernel<true><<<NN, 256, 0, stream>>>(bufC, srcArr, eattr, off, elist, bufB);
    gemm_kernel<EPI_BIAS, true><<<gg, 256, 0, stream>>>(
        bufC, Wself + 2 * DIM * DIM, bufB, Wnbr + 2 * DIM * DIM, convb + 2 * DIM,
        nullptr, nullptr, nullptr, nullptr, nullptr, bufA, DIM, DIM);

    // fused QKV projection: bufQ/bufK/bufV (contiguous) in one launch
    gemm_kernel<EPI_BIAS, false, true><<<dim3(3 * DIM / 64, NN / 64), 256, 0, stream>>>(
        bufA, Wqkv, nullptr, nullptr, bqkv,
        nullptr, nullptr, nullptr, nullptr, nullptr, bufQ, DIM, DIM);

    // flash attention (3-way key split) -> partials, then combine -> bufQ
    attn_kernel<<<dim3(NN / QB, NH, NSPLIT), 256, 0, stream>>>(
        bufQ, bufK, bufV, bufB, bufC, opart2, mpart, lpart);
    attn_combine<<<NN * DIM / 4 / 256, 256, 0, stream>>>(
        bufB, bufC, opart2, mpart, lpart, bufQ);

    // output projection + residual: bufB = bufA + bufQ @ Wo + bo
    gemm_kernel<EPI_BIAS_RES, false><<<gg, 256, 0, stream>>>(
        bufQ, Wo, nullptr, nullptr, bo,
        nullptr, nullptr, nullptr, nullptr, bufA, bufB, DIM, DIM);

    // fc1 + ELU: feats = elu(bufB @ fc1W + fc1b)
    gemm_kernel<EPI_BIAS_ELU, false><<<dim3(F1D / 64, NN / 64), 256, 0, stream>>>(
        bufB, fc1W, nullptr, nullptr, fc1b,
        nullptr, nullptr, nullptr, nullptr, nullptr, feats, DIM, F1D);

    // adapter routing -> out
    adapter_kernel<<<NN, 64, 0, stream>>>(feats, grp, AW1, Ab1, AW2, Ab2, outp);
}

// Round 4
// 455.987 us; speedup vs baseline: 1.6342x; 1.3373x over previous
//
#include <hip/hip_runtime.h>
#include <math.h>

#define NN   4096
#define DIM  256
#define NE   131072
#define NH   4
#define DH   64
#define F1D  128
#define NG   16
#define AD   32

typedef unsigned short u16;
typedef unsigned int   u32;
typedef __attribute__((ext_vector_type(8))) short short8b;
typedef __attribute__((ext_vector_type(4))) float f32x4;

enum { EPI_BIAS = 0, EPI_BNELU = 1, EPI_BIAS_ELU = 2, EPI_BIAS_RES = 3 };

__device__ inline u16 f2bf(float x) {
    u32 u = __float_as_uint(x);
    u += 0x7fffu + ((u >> 16) & 1u);
    return (u16)(u >> 16);
}
__device__ inline float bf2f(u16 h) {
    return __uint_as_float(((u32)h) << 16);
}
__device__ inline u32 packbf(float a, float b) {
    return (u32)f2bf(a) | ((u32)f2bf(b) << 16);
}

// ---------------- CSR build ----------------
__global__ void csr_count(const int* __restrict__ dst, int* __restrict__ cnt) {
    int e = blockIdx.x * 256 + threadIdx.x;
    atomicAdd(&cnt[dst[e]], 1);
}

__global__ void csr_scan(const int* __restrict__ cnt, int* __restrict__ off) {
    int lane = threadIdx.x;
    int base = lane * (NN / 64);
    int s = 0;
    for (int i = 0; i < NN / 64; ++i) s += cnt[base + i];
    int acc = s;
    #pragma unroll
    for (int o = 1; o < 64; o <<= 1) {
        int t = __shfl_up(acc, o);
        if (lane >= o) acc += t;
    }
    int run = acc - s;
    for (int i = 0; i < NN / 64; ++i) { off[base + i] = run; run += cnt[base + i]; }
    if (lane == 63) off[NN] = run;
}

__global__ void csr_fill(const int* __restrict__ dst, const int* __restrict__ off,
                         int* __restrict__ cur, int* __restrict__ elist) {
    int e = blockIdx.x * 256 + threadIdx.x;
    int d = dst[e];
    int pos = off[d] + atomicAdd(&cur[d], 1);
    elist[pos] = e;
}

// ---------------- neighbor aggregation ----------------
template<bool LAST>
__global__ __launch_bounds__(256) void agg_kernel(
    const float* __restrict__ x, const int* __restrict__ src,
    const float* __restrict__ eattr, const int* __restrict__ off,
    const int* __restrict__ elist, float* __restrict__ agg)
{
    int n = blockIdx.x;
    int d = threadIdx.x;
    int j0 = off[n], j1 = off[n + 1];
    float acc = 0.f;
    for (int j = j0; j < j1; ++j) {
        int e = elist[j];
        int s = src[e];
        float w = LAST ? eattr[e] : 1.f;
        acc = fmaf(x[(size_t)s * DIM + d], w, acc);
    }
    agg[(size_t)n * DIM + d] = acc;
}

// ---------------- fp32 tiled GEMM, 64x64 tile, BK=16, 4x4 microtile -------
// QKV mode: writes ONLY bf16 hi/lo Q,K (Q pre-scaled by 1/8) and transposed
// bf16 V^T [DIM][NN] for the MFMA attention.
template<int EPI, bool DUAL, bool QKV = false>
__global__ __launch_bounds__(256) void gemm_kernel(
    const float* __restrict__ A0, const float* __restrict__ B0,
    const float* __restrict__ A1, const float* __restrict__ B1,
    const float* __restrict__ bias,
    const float* __restrict__ gamma, const float* __restrict__ beta,
    const float* __restrict__ bnmean, const float* __restrict__ bnvar,
    const float* __restrict__ resid,
    float* __restrict__ out, int K, int M,
    u16* __restrict__ qh_o, u16* __restrict__ ql_o,
    u16* __restrict__ kh_o, u16* __restrict__ kl_o,
    u16* __restrict__ vt_o)
{
    __shared__ float As[16][68];
    __shared__ float Bs[16][64];

    const int tid  = threadIdx.x;
    const int row0 = blockIdx.y * 64;
    const int c0raw = blockIdx.x * 64;
    const int mat  = QKV ? (c0raw >> 8) : 0;
    const int col0 = QKV ? (c0raw & 255) : c0raw;
    const float* Bp = QKV ? B0 + (size_t)mat * K * M : B0;
    const float* biasp = QKV ? bias + mat * M : bias;

    const int ty = tid >> 4;
    const int tx = tid & 15;
    const int lrow = tid >> 2;
    const int lk4  = (tid & 3) * 4;
    const int bk   = tid >> 4;
    const int bc4  = (tid & 15) * 4;

    float acc[4][4] = {};
    const int kTot = DUAL ? 2 * K : K;
    for (int k0 = 0; k0 < kTot; k0 += 16) {
        const bool ph1 = DUAL && (k0 >= K);
        const float* A = ph1 ? A1 : A0;
        const float* B = ph1 ? B1 : Bp;
        const int kb = ph1 ? (k0 - K) : k0;
        float4 av = *(const float4*)&A[(size_t)(row0 + lrow) * K + kb + lk4];
        float4 bv = *(const float4*)&B[(size_t)(kb + bk) * M + col0 + bc4];
        __syncthreads();
        As[lk4 + 0][lrow] = av.x;
        As[lk4 + 1][lrow] = av.y;
        As[lk4 + 2][lrow] = av.z;
        As[lk4 + 3][lrow] = av.w;
        *(float4*)&Bs[bk][bc4] = bv;
        __syncthreads();
        #pragma unroll
        for (int kk = 0; kk < 16; ++kk) {
            float4 a = *(const float4*)&As[kk][ty * 4];
            float4 b = *(const float4*)&Bs[kk][tx * 4];
            acc[0][0] = fmaf(a.x, b.x, acc[0][0]);
            acc[0][1] = fmaf(a.x, b.y, acc[0][1]);
            acc[0][2] = fmaf(a.x, b.z, acc[0][2]);
            acc[0][3] = fmaf(a.x, b.w, acc[0][3]);
            acc[1][0] = fmaf(a.y, b.x, acc[1][0]);
            acc[1][1] = fmaf(a.y, b.y, acc[1][1]);
            acc[1][2] = fmaf(a.y, b.z, acc[1][2]);
            acc[1][3] = fmaf(a.y, b.w, acc[1][3]);
            acc[2][0] = fmaf(a.z, b.x, acc[2][0]);
            acc[2][1] = fmaf(a.z, b.y, acc[2][1]);
            acc[2][2] = fmaf(a.z, b.z, acc[2][2]);
            acc[2][3] = fmaf(a.z, b.w, acc[2][3]);
            acc[3][0] = fmaf(a.w, b.x, acc[3][0]);
            acc[3][1] = fmaf(a.w, b.y, acc[3][1]);
            acc[3][2] = fmaf(a.w, b.z, acc[3][2]);
            acc[3][3] = fmaf(a.w, b.w, acc[3][3]);
        }
    }
    if constexpr (QKV) {
        if (mat < 2) {
            const float s = (mat == 0) ? 0.125f : 1.0f;
            u16* hi = (mat == 0) ? qh_o : kh_o;
            u16* lo = (mat == 0) ? ql_o : kl_o;
            #pragma unroll
            for (int i = 0; i < 4; ++i) {
                const int r = row0 + ty * 4 + i;
                const int c = col0 + tx * 4;
                u32 wh[2], wl[2];
                #pragma unroll
                for (int g = 0; g < 2; ++g) {
                    float v0 = (acc[i][g * 2]     + biasp[c + g * 2])     * s;
                    float v1 = (acc[i][g * 2 + 1] + biasp[c + g * 2 + 1]) * s;
                    u16 h0 = f2bf(v0), h1 = f2bf(v1);
                    float l0 = v0 - bf2f(h0), l1 = v1 - bf2f(h1);
                    wh[g] = (u32)h0 | ((u32)h1 << 16);
                    wl[g] = packbf(l0, l1);
                }
                *(uint2*)&hi[(size_t)r * DIM + c] = make_uint2(wh[0], wh[1]);
                *(uint2*)&lo[(size_t)r * DIM + c] = make_uint2(wl[0], wl[1]);
            }
        } else {
            #pragma unroll
            for (int j = 0; j < 4; ++j) {
                const int c = col0 + tx * 4 + j;
                const int r = row0 + ty * 4;
                float v0 = acc[0][j] + biasp[c];
                float v1 = acc[1][j] + biasp[c];
                float v2 = acc[2][j] + biasp[c];
                float v3 = acc[3][j] + biasp[c];
                *(uint2*)&vt_o[(size_t)c * NN + r] =
                    make_uint2(packbf(v0, v1), packbf(v2, v3));
            }
        }
    } else {
        #pragma unroll
        for (int i = 0; i < 4; ++i) {
            const int r = row0 + ty * 4 + i;
            #pragma unroll
            for (int j = 0; j < 4; ++j) {
                const int c = col0 + tx * 4 + j;
                float v = acc[i][j] + biasp[c];
                if (EPI == EPI_BNELU) {
                    v = gamma[c] * (v - bnmean[c]) * rsqrtf(bnvar[c] + 1e-5f) + beta[c];
                    v = v > 0.f ? v : expm1f(v);
                } else if (EPI == EPI_BIAS_ELU) {
                    v = v > 0.f ? v : expm1f(v);
                } else if (EPI == EPI_BIAS_RES) {
                    v += resid[(size_t)r * M + c];
                }
                out[(size_t)r * M + c] = v;
            }
        }
    }
}

// ---------------- MFMA flash attention -----------------------------------
// 64x64 tiles. QK^T emulated fp32 via bf16 hi/lo (3 mfma passes); PV bf16.
// 4 waves: wave w -> S quadrant (qh=w&1, kh=w>>1); PV quadrant (qh=w&1, dh=w>>1).
// Softmax in registers (xor-shfl in 16-lane groups; cross-wave via mhalf/lhalf).
#define QB 64
#define KB 64
#define NSPLIT 2
#define KPAD 80
#define PTP 66

__global__ __launch_bounds__(256, 2) void attn_kernel(
    const u16* __restrict__ qhi, const u16* __restrict__ qlo,
    const u16* __restrict__ khi, const u16* __restrict__ klo,
    const u16* __restrict__ vT,
    float* __restrict__ op0, float* __restrict__ op1,
    float* __restrict__ mpart, float* __restrict__ lpart)
{
    __shared__ u16 Qh[64][KPAD], Ql[64][KPAD];
    __shared__ u16 Kh[64][KPAD], Kl[64][KPAD];
    __shared__ u16 Vt[64][KPAD];
    __shared__ u16 PT[64][PTP];               // P^T bf16 [k][q]
    __shared__ float mhalf[2][64], lhalf[2][64], frow[64];

    const int tid = threadIdx.x;
    const int h   = blockIdx.y;
    const int q0  = blockIdx.x * QB;
    const int sp  = blockIdx.z;
    const int key0base = sp * (NN / NSPLIT);
    const int NT = NN / NSPLIT / KB;

    const int w   = tid >> 6;
    const int l   = tid & 63;
    const int l15 = l & 15, h4 = l >> 4;
    const int qh  = w & 1, kh = w >> 1;

    const int lrow = tid & 63, lseg = tid >> 6;   // loader mapping
    const int gq = h * DH + lseg * 16;            // dim offset for row-major ld

    {   // stage Q (once)
        const u16* s0 = qhi + (size_t)(q0 + lrow) * DIM + gq;
        const u16* s1 = qlo + (size_t)(q0 + lrow) * DIM + gq;
        uint4 a = ((const uint4*)s0)[0], b = ((const uint4*)s0)[1];
        uint4 c = ((const uint4*)s1)[0], d = ((const uint4*)s1)[1];
        *(uint4*)&Qh[lrow][lseg * 16]     = a;
        *(uint4*)&Qh[lrow][lseg * 16 + 8] = b;
        *(uint4*)&Ql[lrow][lseg * 16]     = c;
        *(uint4*)&Ql[lrow][lseg * 16 + 8] = d;
    }
    // prefetch K/V tile 0 into registers
    uint4 ska, skb, sla, slb, sva, svb;
    {
        const u16* s0 = khi + (size_t)(key0base + lrow) * DIM + gq;
        const u16* s1 = klo + (size_t)(key0base + lrow) * DIM + gq;
        const u16* s2 = vT + (size_t)(h * DH + lrow) * NN + key0base + lseg * 16;
        ska = ((const uint4*)s0)[0]; skb = ((const uint4*)s0)[1];
        sla = ((const uint4*)s1)[0]; slb = ((const uint4*)s1)[1];
        sva = ((const uint4*)s2)[0]; svb = ((const uint4*)s2)[1];
    }
    __syncthreads();                              // Q staged

    // hoist Q fragments: [qb][kchunk][hi/lo]
    short8b qf[2][2][2];
    #pragma unroll
    for (int qb = 0; qb < 2; ++qb)
        #pragma unroll
        for (int kc = 0; kc < 2; ++kc) {
            const int r = qh * 32 + qb * 16 + l15;
            const int dc = kc * 32 + h4 * 8;
            qf[qb][kc][0] = *(const short8b*)&Qh[r][dc];
            qf[qb][kc][1] = *(const short8b*)&Ql[r][dc];
        }

    const f32x4 z4 = {0.f, 0.f, 0.f, 0.f};
    f32x4 oacc[2][2] = {{z4, z4}, {z4, z4}};
    float m_run[2][4], l_run[2][4];
    #pragma unroll
    for (int qb = 0; qb < 2; ++qb)
        #pragma unroll
        for (int i = 0; i < 4; ++i) { m_run[qb][i] = -3.0e38f; l_run[qb][i] = 0.f; }

    for (int kt = 0; kt < NT; ++kt) {
        // write staged K/V regs to LDS
        *(uint4*)&Kh[lrow][lseg * 16]     = ska;
        *(uint4*)&Kh[lrow][lseg * 16 + 8] = skb;
        *(uint4*)&Kl[lrow][lseg * 16]     = sla;
        *(uint4*)&Kl[lrow][lseg * 16 + 8] = slb;
        *(uint4*)&Vt[lrow][lseg * 16]     = sva;
        *(uint4*)&Vt[lrow][lseg * 16 + 8] = svb;
        __syncthreads();                          // B: tile staged

        // ---- S = Q K^T (3-pass hi/lo) ----
        f32x4 sc[2][2] = {{z4, z4}, {z4, z4}};
        #pragma unroll
        for (int kc = 0; kc < 2; ++kc) {
            short8b kfh[2], kfl[2];
            #pragma unroll
            for (int kcb = 0; kcb < 2; ++kcb) {
                const int r = kh * 32 + kcb * 16 + l15;
                const int dc = kc * 32 + h4 * 8;
                kfh[kcb] = *(const short8b*)&Kh[r][dc];
                kfl[kcb] = *(const short8b*)&Kl[r][dc];
            }
            #pragma unroll
            for (int qb = 0; qb < 2; ++qb)
                #pragma unroll
                for (int kcb = 0; kcb < 2; ++kcb) {
                    sc[qb][kcb] = __builtin_amdgcn_mfma_f32_16x16x32_bf16(
                        qf[qb][kc][0], kfh[kcb], sc[qb][kcb], 0, 0, 0);
                    sc[qb][kcb] = __builtin_amdgcn_mfma_f32_16x16x32_bf16(
                        qf[qb][kc][0], kfl[kcb], sc[qb][kcb], 0, 0, 0);
                    sc[qb][kcb] = __builtin_amdgcn_mfma_f32_16x16x32_bf16(
                        qf[qb][kc][1], kfh[kcb], sc[qb][kcb], 0, 0, 0);
                }
        }
        // prefetch next tile while softmax runs
        if (kt + 1 < NT) {
            const int key0 = key0base + (kt + 1) * KB;
            const u16* s0 = khi + (size_t)(key0 + lrow) * DIM + gq;
            const u16* s1 = klo + (size_t)(key0 + lrow) * DIM + gq;
            const u16* s2 = vT + (size_t)(h * DH + lrow) * NN + key0 + lseg * 16;
            ska = ((const uint4*)s0)[0]; skb = ((const uint4*)s0)[1];
            sla = ((const uint4*)s1)[0]; slb = ((const uint4*)s1)[1];
            sva = ((const uint4*)s2)[0]; svb = ((const uint4*)s2)[1];
        }
        // ---- softmax part 1: wave-half row max ----
        float pm[2][4];
        #pragma unroll
        for (int qb = 0; qb < 2; ++qb)
            #pragma unroll
            for (int i = 0; i < 4; ++i)
                pm[qb][i] = fmaxf(sc[qb][0][i], sc[qb][1][i]);
        #pragma unroll
        for (int off = 1; off < 16; off <<= 1)
            #pragma unroll
            for (int qb = 0; qb < 2; ++qb)
                #pragma unroll
                for (int i = 0; i < 4; ++i)
                    pm[qb][i] = fmaxf(pm[qb][i], __shfl_xor(pm[qb][i], off));
        if (l15 == 0) {
            #pragma unroll
            for (int qb = 0; qb < 2; ++qb)
                #pragma unroll
                for (int i = 0; i < 4; ++i)
                    mhalf[kh][qh * 32 + qb * 16 + h4 * 4 + i] = pm[qb][i];
        }
        __syncthreads();                          // C: mhalf visible

        // ---- softmax part 2: exp, sums, P^T, frow ----
        float f[2][4], lsum[2][4], p[2][2][4];
        #pragma unroll
        for (int qb = 0; qb < 2; ++qb)
            #pragma unroll
            for (int i = 0; i < 4; ++i) {
                const int r = qh * 32 + qb * 16 + h4 * 4 + i;
                const float mnew = fmaxf(m_run[qb][i],
                                         fmaxf(mhalf[0][r], mhalf[1][r]));
                f[qb][i] = __expf(m_run[qb][i] - mnew);
                m_run[qb][i] = mnew;
                p[qb][0][i] = __expf(sc[qb][0][i] - mnew);
                p[qb][1][i] = __expf(sc[qb][1][i] - mnew);
                float ls = p[qb][0][i] + p[qb][1][i];
                #pragma unroll
                for (int off = 1; off < 16; off <<= 1) ls += __shfl_xor(ls, off);
                lsum[qb][i] = ls;
            }
        if (l15 == 0) {
            #pragma unroll
            for (int qb = 0; qb < 2; ++qb)
                #pragma unroll
                for (int i = 0; i < 4; ++i)
                    lhalf[kh][qh * 32 + qb * 16 + h4 * 4 + i] = lsum[qb][i];
            if (kh == 0)
                #pragma unroll
                for (int qb = 0; qb < 2; ++qb)
                    #pragma unroll
                    for (int i = 0; i < 4; ++i)
                        frow[qh * 32 + qb * 16 + h4 * 4 + i] = f[qb][i];
        }
        #pragma unroll
        for (int qb = 0; qb < 2; ++qb)
            #pragma unroll
            for (int kcb = 0; kcb < 2; ++kcb) {
                const int kk = kh * 32 + kcb * 16 + l15;
                const int qq = qh * 32 + qb * 16 + h4 * 4;
                *(u32*)&PT[kk][qq]     = packbf(p[qb][kcb][0], p[qb][kcb][1]);
                *(u32*)&PT[kk][qq + 2] = packbf(p[qb][kcb][2], p[qb][kcb][3]);
            }
        __syncthreads();                          // D: P^T, frow, lhalf visible

        // ---- running denominator (replicated across kh pairs) ----
        #pragma unroll
        for (int qb = 0; qb < 2; ++qb)
            #pragma unroll
            for (int i = 0; i < 4; ++i) {
                const int r = qh * 32 + qb * 16 + h4 * 4 + i;
                l_run[qb][i] = l_run[qb][i] * f[qb][i] + lsum[qb][i] + lhalf[kh ^ 1][r];
            }

        // ---- PV: o^T += V^T * P^T ----
        float fq[2];
        #pragma unroll
        for (int qb = 0; qb < 2; ++qb) fq[qb] = frow[qh * 32 + qb * 16 + l15];
        #pragma unroll
        for (int db = 0; db < 2; ++db)
            #pragma unroll
            for (int qb = 0; qb < 2; ++qb)
                oacc[db][qb] *= fq[qb];
        #pragma unroll
        for (int kc = 0; kc < 2; ++kc) {
            short8b vf[2];
            #pragma unroll
            for (int db = 0; db < 2; ++db)
                vf[db] = *(const short8b*)&Vt[kh * 32 + db * 16 + l15][kc * 32 + h4 * 8];
            union { short8b v; u16 u[8]; } pf[2];
            #pragma unroll
            for (int qb = 0; qb < 2; ++qb) {
                const int qq = qh * 32 + qb * 16 + l15;
                #pragma unroll
                for (int j = 0; j < 8; ++j)
                    pf[qb].u[j] = PT[kc * 32 + h4 * 8 + j][qq];
            }
            #pragma unroll
            for (int db = 0; db < 2; ++db)
                #pragma unroll
                for (int qb = 0; qb < 2; ++qb)
                    oacc[db][qb] = __builtin_amdgcn_mfma_f32_16x16x32_bf16(
                        vf[db], pf[qb].v, oacc[db][qb], 0, 0, 0);
        }
        __syncthreads();                          // A': PV done, buffers free
    }

    // epilogue: unnormalized o^T partial + (m,l)
    float* ob = sp ? op1 : op0;
    #pragma unroll
    for (int db = 0; db < 2; ++db)
        #pragma unroll
        for (int qb = 0; qb < 2; ++qb) {
            const int qq = q0 + qh * 32 + qb * 16 + l15;
            const int d0 = h * DH + kh * 32 + db * 16 + h4 * 4;
            *(f32x4*)&ob[(size_t)qq * DIM + d0] = oacc[db][qb];
        }
    if (kh == 0 && l15 == 0) {
        #pragma unroll
        for (int qb = 0; qb < 2; ++qb)
            #pragma unroll
            for (int i = 0; i < 4; ++i) {
                const int r = qh * 32 + qb * 16 + h4 * 4 + i;
                mpart[((size_t)sp * NN + q0 + r) * NH + h] = m_run[qb][i];
                lpart[((size_t)sp * NN + q0 + r) * NH + h] = l_run[qb][i];
            }
    }
}

// merge the NSPLIT partials
__global__ __launch_bounds__(256) void attn_combine(
    const float* __restrict__ o0, const float* __restrict__ o1,
    const float* __restrict__ mp, const float* __restrict__ lp,
    float* __restrict__ out)
{
    const int gid = blockIdx.x * 256 + threadIdx.x;
    const int row = gid >> 6;
    const int c4  = (gid & 63) * 4;
    const int h   = c4 >> 6;
    const float m0 = mp[row * NH + h];
    const float m1 = mp[(NN + row) * NH + h];
    const float M  = fmaxf(m0, m1);
    const float w0 = __expf(m0 - M), w1 = __expf(m1 - M);
    const float inv = 1.f / (lp[row * NH + h] * w0 + lp[(NN + row) * NH + h] * w1);
    const float4 a = *(const float4*)&o0[(size_t)row * DIM + c4];
    const float4 b = *(const float4*)&o1[(size_t)row * DIM + c4];
    float4 r;
    r.x = (a.x * w0 + b.x * w1) * inv;
    r.y = (a.y * w0 + b.y * w1) * inv;
    r.z = (a.z * w0 + b.z * w1) * inv;
    r.w = (a.w * w0 + b.w * w1) * inv;
    *(float4*)&out[(size_t)row * DIM + c4] = r;
}

// ---------------- per-node group adapter ----------------
__global__ __launch_bounds__(64) void adapter_kernel(
    const float* __restrict__ feats, const int* __restrict__ grp,
    const float* __restrict__ AW1, const float* __restrict__ Ab1,
    const float* __restrict__ AW2, const float* __restrict__ Ab2,
    float* __restrict__ out)
{
    const int n = blockIdx.x;
    const int lane = threadIdx.x;
    __shared__ float f[F1D];
    f[lane]      = feats[(size_t)n * F1D + lane];
    f[lane + 64] = feats[(size_t)n * F1D + 64 + lane];
    __syncthreads();
    const int g = grp[n];
    const float* W1 = AW1 + (size_t)g * F1D * AD;
    const int a = lane & 31;
    const int half = lane >> 5;
    float hsum = 0.f;
    for (int d = 0; d < 64; ++d)
        hsum = fmaf(f[half * 64 + d], W1[(half * 64 + d) * AD + a], hsum);
    hsum += __shfl_xor(hsum, 32);
    hsum = fmaxf(hsum + Ab1[g * AD + a], 0.f);
    float p = hsum * AW2[g * AD + a];
    #pragma unroll
    for (int mm = 1; mm < 32; mm <<= 1) p += __shfl_xor(p, mm);
    if (lane == 0) out[n] = p + Ab2[g];
}

// ---------------- host-side orchestration ----------------
extern "C" void kernel_launch(void* const* d_in, const int* in_sizes, int n_in,
                              void* d_out, int out_size, void* d_ws, size_t ws_size,
                              hipStream_t stream)
{
    const float* x_in   = (const float*)d_in[0];
    const float* eattr  = (const float*)d_in[1];
    const float* Wself  = (const float*)d_in[2];
    const float* Wnbr   = (const float*)d_in[3];
    const float* convb  = (const float*)d_in[4];
    const float* gamma  = (const float*)d_in[5];
    const float* beta   = (const float*)d_in[6];
    const float* bnmean = (const float*)d_in[7];
    const float* bnvar  = (const float*)d_in[8];
    const float* Wqkv   = (const float*)d_in[9];
    const float* bqkv   = (const float*)d_in[10];
    const float* Wo     = (const float*)d_in[11];
    const float* bo     = (const float*)d_in[12];
    const float* fc1W   = (const float*)d_in[13];
    const float* fc1b   = (const float*)d_in[14];
    const float* AW1    = (const float*)d_in[15];
    const float* Ab1    = (const float*)d_in[16];
    const float* AW2    = (const float*)d_in[17];
    const float* Ab2    = (const float*)d_in[18];
    const int*   eidx   = (const int*)d_in[19];
    const int*   grp    = (const int*)d_in[20];
    const int* srcArr = eidx;
    const int* dstArr = eidx + NE;

    float* fws = (float*)d_ws;
    const size_t NM = (size_t)NN * DIM;
    float* bufA   = fws;                 // x L0 / x L2 (residual)
    float* bufB   = fws + NM;            // agg scratch; combine out
    float* bufC   = fws + 2 * NM;        // x L1; attn opart0; Wo out
    float* opart1 = fws + 3 * NM;
    float* feats  = fws + 4 * NM;        // NN x F1D = NM/2
    float* mpart  = fws + 4 * NM + NM / 2;        // [2][NN][NH]
    float* lpart  = mpart + 2 * NN * NH;
    u16* qhi = (u16*)(lpart + 2 * NN * NH);       // NN*DIM u16 each
    u16* qlo = qhi + NM;
    u16* khi = qlo + NM;
    u16* klo = khi + NM;
    u16* vt  = klo + NM;                          // [DIM][NN]
    int* iws   = (int*)(vt + NM);
    int* off   = iws;
    int* cur   = iws + NN + 1;
    int* elist = iws + 2 * NN + 1;
    float* outp = (float*)d_out;

    // CSR build
    hipMemsetAsync(cur, 0, NN * sizeof(int), stream);
    csr_count<<<NE / 256, 256, 0, stream>>>(dstArr, cur);
    csr_scan<<<1, 64, 0, stream>>>(cur, off);
    hipMemsetAsync(cur, 0, NN * sizeof(int), stream);
    csr_fill<<<NE / 256, 256, 0, stream>>>(dstArr, off, cur, elist);

    const dim3 gg(DIM / 64, NN / 64);

    // conv layer 0: x_in -> bufA
    agg_kernel<false><<<NN, 256, 0, stream>>>(x_in, srcArr, eattr, off, elist, bufB);
    gemm_kernel<EPI_BNELU, true><<<gg, 256, 0, stream>>>(
        x_in, Wself, bufB, Wnbr, convb, gamma, beta, bnmean, bnvar,
        nullptr, bufA, DIM, DIM, nullptr, nullptr, nullptr, nullptr, nullptr);
    // conv layer 1: bufA -> bufC
    agg_kernel<false><<<NN, 256, 0, stream>>>(bufA, srcArr, eattr, off, elist, bufB);
    gemm_kernel<EPI_BNELU, true><<<gg, 256, 0, stream>>>(
        bufA, Wself + DIM * DIM, bufB, Wnbr + DIM * DIM, convb + DIM,
        gamma + DIM, beta + DIM, bnmean + DIM, bnvar + DIM,
        nullptr, bufC, DIM, DIM, nullptr, nullptr, nullptr, nullptr, nullptr);
    // conv layer 2: bufC -> bufA
    agg_kernel<true><<<NN, 256, 0, stream>>>(bufC, srcArr, eattr, off, elist, bufB);
    gemm_kernel<EPI_BIAS, true><<<gg, 256, 0, stream>>>(
        bufC, Wself + 2 * DIM * DIM, bufB, Wnbr + 2 * DIM * DIM, convb + 2 * DIM,
        nullptr, nullptr, nullptr, nullptr, nullptr, bufA, DIM, DIM,
        nullptr, nullptr, nullptr, nullptr, nullptr);

    // fused QKV projection -> bf16 hi/lo Q,K + V^T
    gemm_kernel<EPI_BIAS, false, true><<<dim3(3 * DIM / 64, NN / 64), 256, 0, stream>>>(
        bufA, Wqkv, nullptr, nullptr, bqkv,
        nullptr, nullptr, nullptr, nullptr, nullptr, nullptr, DIM, DIM,
        qhi, qlo, khi, klo, vt);

    // MFMA flash attention (2-way key split) -> partials, combine -> bufB
    attn_kernel<<<dim3(NN / QB, NH, NSPLIT), 256, 0, stream>>>(
        qhi, qlo, khi, klo, vt, bufC, opart1, mpart, lpart);
    attn_combine<<<NN * DIM / 4 / 256, 256, 0, stream>>>(
        bufC, opart1, mpart, lpart, bufB);

    // output projection + residual: bufC = bufA + bufB @ Wo + bo
    gemm_kernel<EPI_BIAS_RES, false><<<gg, 256, 0, stream>>>(
        bufB, Wo, nullptr, nullptr, bo,
        nullptr, nullptr, nullptr, nullptr, bufA, bufC, DIM, DIM,
        nullptr, nullptr, nullptr, nullptr, nullptr);

    // fc1 + ELU: feats = elu(bufC @ fc1W + fc1b)
    gemm_kernel<EPI_BIAS_ELU, false><<<dim3(F1D / 64, NN / 64), 256, 0, stream>>>(
        bufC, fc1W, nullptr, nullptr, fc1b,
        nullptr, nullptr, nullptr, nullptr, nullptr, feats, DIM, F1D,
        nullptr, nullptr, nullptr, nullptr, nullptr);

    // adapter routing -> out
    adapter_kernel<<<NN, 64, 0, stream>>>(feats, grp, AW1, Ab1, AW2, Ab2, outp);
}

// Round 5
// 328.041 us; speedup vs baseline: 2.2716x; 1.3900x over previous
//
#include <hip/hip_runtime.h>
#include <math.h>

#define NN   4096
#define DIM  256
#define NE   131072
#define NH   4
#define DH   64
#define F1D  128
#define NG   16
#define AD   32

typedef unsigned short u16;
typedef unsigned int   u32;
typedef __attribute__((ext_vector_type(8))) short short8b;
typedef __attribute__((ext_vector_type(4))) float f32x4;

enum { EPI_BIAS = 0, EPI_BNELU = 1, EPI_BIAS_ELU = 2, EPI_BIAS_RES = 3 };

__device__ inline u16 f2bf(float x) {
    u32 u = __float_as_uint(x);
    u += 0x7fffu + ((u >> 16) & 1u);
    return (u16)(u >> 16);
}
__device__ inline float bf2f(u16 h) {
    return __uint_as_float(((u32)h) << 16);
}
__device__ inline u32 packbf(float a, float b) {
    return (u32)f2bf(a) | ((u32)f2bf(b) << 16);
}

// ---------------- CSR build ----------------
__global__ void csr_count(const int* __restrict__ dst, int* __restrict__ cnt) {
    int e = blockIdx.x * 256 + threadIdx.x;
    atomicAdd(&cnt[dst[e]], 1);
}

__global__ void csr_scan(const int* __restrict__ cnt, int* __restrict__ off) {
    int lane = threadIdx.x;
    int base = lane * (NN / 64);
    int s = 0;
    for (int i = 0; i < NN / 64; ++i) s += cnt[base + i];
    int acc = s;
    #pragma unroll
    for (int o = 1; o < 64; o <<= 1) {
        int t = __shfl_up(acc, o);
        if (lane >= o) acc += t;
    }
    int run = acc - s;
    for (int i = 0; i < NN / 64; ++i) { off[base + i] = run; run += cnt[base + i]; }
    if (lane == 63) off[NN] = run;
}

// store src node id and edge weight directly (drops one indirection in agg)
__global__ void csr_fill(const int* __restrict__ dst, const int* __restrict__ src,
                         const float* __restrict__ eattr, const int* __restrict__ off,
                         int* __restrict__ cur, int* __restrict__ esrc,
                         float* __restrict__ ewt) {
    int e = blockIdx.x * 256 + threadIdx.x;
    int d = dst[e];
    int pos = off[d] + atomicAdd(&cur[d], 1);
    esrc[pos] = src[e];
    ewt[pos]  = eattr[e];
}

// ---------------- neighbor aggregation: 1 wave per node, float4, unroll 4 --
template<bool LAST>
__global__ __launch_bounds__(256) void agg_kernel(
    const float* __restrict__ x, const int* __restrict__ esrc,
    const float* __restrict__ ewt, const int* __restrict__ off,
    float* __restrict__ agg)
{
    const int node = blockIdx.x * 4 + (threadIdx.x >> 6);
    const int lane = threadIdx.x & 63;
    const int d4 = lane * 4;
    int j = off[node];
    const int j1 = off[node + 1];
    float4 acc = make_float4(0.f, 0.f, 0.f, 0.f);
    for (; j + 4 <= j1; j += 4) {
        const int s0 = esrc[j], s1 = esrc[j + 1], s2 = esrc[j + 2], s3 = esrc[j + 3];
        const float4 x0 = *(const float4*)&x[(size_t)s0 * DIM + d4];
        const float4 x1 = *(const float4*)&x[(size_t)s1 * DIM + d4];
        const float4 x2 = *(const float4*)&x[(size_t)s2 * DIM + d4];
        const float4 x3 = *(const float4*)&x[(size_t)s3 * DIM + d4];
        const float w0 = LAST ? ewt[j]     : 1.f;
        const float w1 = LAST ? ewt[j + 1] : 1.f;
        const float w2 = LAST ? ewt[j + 2] : 1.f;
        const float w3 = LAST ? ewt[j + 3] : 1.f;
        acc.x = fmaf(x0.x, w0, acc.x); acc.y = fmaf(x0.y, w0, acc.y);
        acc.z = fmaf(x0.z, w0, acc.z); acc.w = fmaf(x0.w, w0, acc.w);
        acc.x = fmaf(x1.x, w1, acc.x); acc.y = fmaf(x1.y, w1, acc.y);
        acc.z = fmaf(x1.z, w1, acc.z); acc.w = fmaf(x1.w, w1, acc.w);
        acc.x = fmaf(x2.x, w2, acc.x); acc.y = fmaf(x2.y, w2, acc.y);
        acc.z = fmaf(x2.z, w2, acc.z); acc.w = fmaf(x2.w, w2, acc.w);
        acc.x = fmaf(x3.x, w3, acc.x); acc.y = fmaf(x3.y, w3, acc.y);
        acc.z = fmaf(x3.z, w3, acc.z); acc.w = fmaf(x3.w, w3, acc.w);
    }
    for (; j < j1; ++j) {
        const int s = esrc[j];
        const float w = LAST ? ewt[j] : 1.f;
        const float4 xv = *(const float4*)&x[(size_t)s * DIM + d4];
        acc.x = fmaf(xv.x, w, acc.x); acc.y = fmaf(xv.y, w, acc.y);
        acc.z = fmaf(xv.z, w, acc.z); acc.w = fmaf(xv.w, w, acc.w);
    }
    *(float4*)&agg[(size_t)node * DIM + d4] = acc;
}

// ---------------- fp32 tiled GEMM, 64x64 tile, BK=16, register prefetch ---
// QKV mode: writes bf16 hi/lo Q,K (Q pre-scaled by 1/8) and bf16 V^T.
template<int EPI, bool DUAL, bool QKV = false>
__global__ __launch_bounds__(256) void gemm_kernel(
    const float* __restrict__ A0, const float* __restrict__ B0,
    const float* __restrict__ A1, const float* __restrict__ B1,
    const float* __restrict__ bias,
    const float* __restrict__ gamma, const float* __restrict__ beta,
    const float* __restrict__ bnmean, const float* __restrict__ bnvar,
    const float* __restrict__ resid,
    float* __restrict__ out, int K, int M,
    u16* __restrict__ qh_o, u16* __restrict__ ql_o,
    u16* __restrict__ kh_o, u16* __restrict__ kl_o,
    u16* __restrict__ vt_o)
{
    __shared__ float As[16][68];
    __shared__ float Bs[16][64];

    const int tid  = threadIdx.x;
    const int row0 = blockIdx.y * 64;
    const int c0raw = blockIdx.x * 64;
    const int mat  = QKV ? (c0raw >> 8) : 0;
    const int col0 = QKV ? (c0raw & 255) : c0raw;
    const float* Bp = QKV ? B0 + (size_t)mat * K * M : B0;
    const float* biasp = QKV ? bias + mat * M : bias;

    const int ty = tid >> 4;
    const int tx = tid & 15;
    const int lrow = tid >> 2;
    const int lk4  = (tid & 3) * 4;
    const int bk   = tid >> 4;
    const int bc4  = (tid & 15) * 4;

    float acc[4][4] = {};
    const int kTot = DUAL ? 2 * K : K;

    float4 av, bv;
    {   // initial load (k0 = 0)
        av = *(const float4*)&A0[(size_t)(row0 + lrow) * K + lk4];
        bv = *(const float4*)&Bp[(size_t)bk * M + col0 + bc4];
    }
    for (int k0 = 0; k0 < kTot; k0 += 16) {
        __syncthreads();
        As[lk4 + 0][lrow] = av.x;
        As[lk4 + 1][lrow] = av.y;
        As[lk4 + 2][lrow] = av.z;
        As[lk4 + 3][lrow] = av.w;
        *(float4*)&Bs[bk][bc4] = bv;
        // prefetch next k-tile into registers (overlaps with compute)
        if (k0 + 16 < kTot) {
            const int kn = k0 + 16;
            const bool ph1 = DUAL && (kn >= K);
            const float* A = ph1 ? A1 : A0;
            const float* B = ph1 ? B1 : Bp;
            const int kb = ph1 ? (kn - K) : kn;
            av = *(const float4*)&A[(size_t)(row0 + lrow) * K + kb + lk4];
            bv = *(const float4*)&B[(size_t)(kb + bk) * M + col0 + bc4];
        }
        __syncthreads();
        #pragma unroll
        for (int kk = 0; kk < 16; ++kk) {
            float4 a = *(const float4*)&As[kk][ty * 4];
            float4 b = *(const float4*)&Bs[kk][tx * 4];
            acc[0][0] = fmaf(a.x, b.x, acc[0][0]);
            acc[0][1] = fmaf(a.x, b.y, acc[0][1]);
            acc[0][2] = fmaf(a.x, b.z, acc[0][2]);
            acc[0][3] = fmaf(a.x, b.w, acc[0][3]);
            acc[1][0] = fmaf(a.y, b.x, acc[1][0]);
            acc[1][1] = fmaf(a.y, b.y, acc[1][1]);
            acc[1][2] = fmaf(a.y, b.z, acc[1][2]);
            acc[1][3] = fmaf(a.y, b.w, acc[1][3]);
            acc[2][0] = fmaf(a.z, b.x, acc[2][0]);
            acc[2][1] = fmaf(a.z, b.y, acc[2][1]);
            acc[2][2] = fmaf(a.z, b.z, acc[2][2]);
            acc[2][3] = fmaf(a.z, b.w, acc[2][3]);
            acc[3][0] = fmaf(a.w, b.x, acc[3][0]);
            acc[3][1] = fmaf(a.w, b.y, acc[3][1]);
            acc[3][2] = fmaf(a.w, b.z, acc[3][2]);
            acc[3][3] = fmaf(a.w, b.w, acc[3][3]);
        }
    }
    if constexpr (QKV) {
        if (mat < 2) {
            const float s = (mat == 0) ? 0.125f : 1.0f;
            u16* hi = (mat == 0) ? qh_o : kh_o;
            u16* lo = (mat == 0) ? ql_o : kl_o;
            #pragma unroll
            for (int i = 0; i < 4; ++i) {
                const int r = row0 + ty * 4 + i;
                const int c = col0 + tx * 4;
                u32 wh[2], wl[2];
                #pragma unroll
                for (int g = 0; g < 2; ++g) {
                    float v0 = (acc[i][g * 2]     + biasp[c + g * 2])     * s;
                    float v1 = (acc[i][g * 2 + 1] + biasp[c + g * 2 + 1]) * s;
                    u16 h0 = f2bf(v0), h1 = f2bf(v1);
                    float l0 = v0 - bf2f(h0), l1 = v1 - bf2f(h1);
                    wh[g] = (u32)h0 | ((u32)h1 << 16);
                    wl[g] = packbf(l0, l1);
                }
                *(uint2*)&hi[(size_t)r * DIM + c] = make_uint2(wh[0], wh[1]);
                *(uint2*)&lo[(size_t)r * DIM + c] = make_uint2(wl[0], wl[1]);
            }
        } else {
            #pragma unroll
            for (int j = 0; j < 4; ++j) {
                const int c = col0 + tx * 4 + j;
                const int r = row0 + ty * 4;
                float v0 = acc[0][j] + biasp[c];
                float v1 = acc[1][j] + biasp[c];
                float v2 = acc[2][j] + biasp[c];
                float v3 = acc[3][j] + biasp[c];
                *(uint2*)&vt_o[(size_t)c * NN + r] =
                    make_uint2(packbf(v0, v1), packbf(v2, v3));
            }
        }
    } else {
        #pragma unroll
        for (int i = 0; i < 4; ++i) {
            const int r = row0 + ty * 4 + i;
            #pragma unroll
            for (int j = 0; j < 4; ++j) {
                const int c = col0 + tx * 4 + j;
                float v = acc[i][j] + biasp[c];
                if (EPI == EPI_BNELU) {
                    v = gamma[c] * (v - bnmean[c]) * rsqrtf(bnvar[c] + 1e-5f) + beta[c];
                    v = v > 0.f ? v : expm1f(v);
                } else if (EPI == EPI_BIAS_ELU) {
                    v = v > 0.f ? v : expm1f(v);
                } else if (EPI == EPI_BIAS_RES) {
                    v += resid[(size_t)r * M + c];
                }
                out[(size_t)r * M + c] = v;
            }
        }
    }
}

// ---------------- MFMA flash attention -----------------------------------
// 64x64 tiles; QK^T fp32-emulated via bf16 hi/lo (4 mfma passes); PV bf16.
// LDS overlay: Q staging region is reused for K/V tiles after Q-frag hoist;
// P^T + softmax state live past the K/V region. Total 40448 B -> 3 blocks/CU
// (grid 768 with NSPLIT=3 = exactly 3/CU).
#define QB 64
#define KB 64
#define NSPLIT 3
#define NKT (NN / KB)

__global__ __launch_bounds__(256, 3) void attn_kernel(
    const u16* __restrict__ qhi, const u16* __restrict__ qlo,
    const u16* __restrict__ khi, const u16* __restrict__ klo,
    const u16* __restrict__ vT,
    float* __restrict__ op0, float* __restrict__ op1, float* __restrict__ op2,
    float* __restrict__ mpart, float* __restrict__ lpart)
{
    __shared__ u16 lds[20224];            // 40448 B
    u16* Kh = lds;                        // [64][80]
    u16* Kl = lds + 5120;                 // [64][80]
    u16* Vt = lds + 10240;                // [64][80]  (d-major: [d][key])
    u16* Qh = lds;                        // overlay: init phase only
    u16* Ql = lds + 5120;                 // overlay: init phase only
    u16* PTb = lds + 15360;               // [64][66]  P^T bf16 [k][q]
    float* fls = (float*)(lds + 19584);   // 320 floats
    float* mh0 = fls;                     // mhalf[0][64]
    float* mh1 = fls + 64;
    float* lh0 = fls + 128;               // lhalf[0][64]
    float* lh1 = fls + 192;
    float* frow = fls + 256;              // [64]

    const int tid = threadIdx.x;
    const int h   = blockIdx.y;
    const int q0  = blockIdx.x * QB;
    const int sp  = blockIdx.z;
    const int kt0 = (sp * NKT) / NSPLIT;
    const int kt1 = ((sp + 1) * NKT) / NSPLIT;

    const int w   = tid >> 6;
    const int l   = tid & 63;
    const int l15 = l & 15, h4 = l >> 4;
    const int qh  = w & 1, kh = w >> 1;

    const int lrow = tid & 63, lseg = tid >> 6;   // loader mapping
    const int gq = h * DH + lseg * 16;

    {   // stage Q (once, into overlay region)
        const u16* s0 = qhi + (size_t)(q0 + lrow) * DIM + gq;
        const u16* s1 = qlo + (size_t)(q0 + lrow) * DIM + gq;
        uint4 a = ((const uint4*)s0)[0], b = ((const uint4*)s0)[1];
        uint4 c = ((const uint4*)s1)[0], d = ((const uint4*)s1)[1];
        *(uint4*)&Qh[lrow * 80 + lseg * 16]     = a;
        *(uint4*)&Qh[lrow * 80 + lseg * 16 + 8] = b;
        *(uint4*)&Ql[lrow * 80 + lseg * 16]     = c;
        *(uint4*)&Ql[lrow * 80 + lseg * 16 + 8] = d;
    }
    // prefetch K/V tile kt0 into registers
    uint4 ska, skb, sla, slb, sva, svb;
    {
        const int key0 = kt0 * KB;
        const u16* s0 = khi + (size_t)(key0 + lrow) * DIM + gq;
        const u16* s1 = klo + (size_t)(key0 + lrow) * DIM + gq;
        const u16* s2 = vT + (size_t)(h * DH + lrow) * NN + key0 + lseg * 16;
        ska = ((const uint4*)s0)[0]; skb = ((const uint4*)s0)[1];
        sla = ((const uint4*)s1)[0]; slb = ((const uint4*)s1)[1];
        sva = ((const uint4*)s2)[0]; svb = ((const uint4*)s2)[1];
    }
    __syncthreads();                              // Q staged

    // hoist Q fragments: [qb][kchunk][hi/lo]
    short8b qf[2][2][2];
    #pragma unroll
    for (int qb = 0; qb < 2; ++qb)
        #pragma unroll
        for (int kc = 0; kc < 2; ++kc) {
            const int r = qh * 32 + qb * 16 + l15;
            const int dc = kc * 32 + h4 * 8;
            qf[qb][kc][0] = *(const short8b*)&Qh[r * 80 + dc];
            qf[qb][kc][1] = *(const short8b*)&Ql[r * 80 + dc];
        }
    __syncthreads();                              // hoist done; overlay safe

    const f32x4 z4 = {0.f, 0.f, 0.f, 0.f};
    f32x4 oacc[2][2] = {{z4, z4}, {z4, z4}};
    float m_run[2][4], l_run[2][4];
    #pragma unroll
    for (int qb = 0; qb < 2; ++qb)
        #pragma unroll
        for (int i = 0; i < 4; ++i) { m_run[qb][i] = -3.0e38f; l_run[qb][i] = 0.f; }

    for (int kt = kt0; kt < kt1; ++kt) {
        // write staged K/V regs to LDS
        *(uint4*)&Kh[lrow * 80 + lseg * 16]     = ska;
        *(uint4*)&Kh[lrow * 80 + lseg * 16 + 8] = skb;
        *(uint4*)&Kl[lrow * 80 + lseg * 16]     = sla;
        *(uint4*)&Kl[lrow * 80 + lseg * 16 + 8] = slb;
        *(uint4*)&Vt[lrow * 80 + lseg * 16]     = sva;
        *(uint4*)&Vt[lrow * 80 + lseg * 16 + 8] = svb;
        __syncthreads();                          // B: tile staged

        // ---- S = Q K^T (4-pass hi/lo: qh*kh + qh*kl + ql*kh + ql*kl) ----
        f32x4 sc[2][2] = {{z4, z4}, {z4, z4}};
        #pragma unroll
        for (int kc = 0; kc < 2; ++kc) {
            short8b kfh[2], kfl[2];
            #pragma unroll
            for (int kcb = 0; kcb < 2; ++kcb) {
                const int r = kh * 32 + kcb * 16 + l15;
                const int dc = kc * 32 + h4 * 8;
                kfh[kcb] = *(const short8b*)&Kh[r * 80 + dc];
                kfl[kcb] = *(const short8b*)&Kl[r * 80 + dc];
            }
            #pragma unroll
            for (int qb = 0; qb < 2; ++qb)
                #pragma unroll
                for (int kcb = 0; kcb < 2; ++kcb) {
                    sc[qb][kcb] = __builtin_amdgcn_mfma_f32_16x16x32_bf16(
                        qf[qb][kc][0], kfh[kcb], sc[qb][kcb], 0, 0, 0);
                    sc[qb][kcb] = __builtin_amdgcn_mfma_f32_16x16x32_bf16(
                        qf[qb][kc][0], kfl[kcb], sc[qb][kcb], 0, 0, 0);
                    sc[qb][kcb] = __builtin_amdgcn_mfma_f32_16x16x32_bf16(
                        qf[qb][kc][1], kfh[kcb], sc[qb][kcb], 0, 0, 0);
                    sc[qb][kcb] = __builtin_amdgcn_mfma_f32_16x16x32_bf16(
                        qf[qb][kc][1], kfl[kcb], sc[qb][kcb], 0, 0, 0);
                }
        }
        // prefetch next tile while softmax runs
        if (kt + 1 < kt1) {
            const int key0 = (kt + 1) * KB;
            const u16* s0 = khi + (size_t)(key0 + lrow) * DIM + gq;
            const u16* s1 = klo + (size_t)(key0 + lrow) * DIM + gq;
            const u16* s2 = vT + (size_t)(h * DH + lrow) * NN + key0 + lseg * 16;
            ska = ((const uint4*)s0)[0]; skb = ((const uint4*)s0)[1];
            sla = ((const uint4*)s1)[0]; slb = ((const uint4*)s1)[1];
            sva = ((const uint4*)s2)[0]; svb = ((const uint4*)s2)[1];
        }
        // ---- softmax part 1: wave-half row max ----
        float pm[2][4];
        #pragma unroll
        for (int qb = 0; qb < 2; ++qb)
            #pragma unroll
            for (int i = 0; i < 4; ++i)
                pm[qb][i] = fmaxf(sc[qb][0][i], sc[qb][1][i]);
        #pragma unroll
        for (int off = 1; off < 16; off <<= 1)
            #pragma unroll
            for (int qb = 0; qb < 2; ++qb)
                #pragma unroll
                for (int i = 0; i < 4; ++i)
                    pm[qb][i] = fmaxf(pm[qb][i], __shfl_xor(pm[qb][i], off));
        if (l15 == 0) {
            float* mh = kh ? mh1 : mh0;
            #pragma unroll
            for (int qb = 0; qb < 2; ++qb)
                #pragma unroll
                for (int i = 0; i < 4; ++i)
                    mh[qh * 32 + qb * 16 + h4 * 4 + i] = pm[qb][i];
        }
        __syncthreads();                          // C: mhalf visible

        // ---- softmax part 2: exp, sums, P^T, frow ----
        float f[2][4], lsum[2][4], p[2][2][4];
        #pragma unroll
        for (int qb = 0; qb < 2; ++qb)
            #pragma unroll
            for (int i = 0; i < 4; ++i) {
                const int r = qh * 32 + qb * 16 + h4 * 4 + i;
                const float mnew = fmaxf(m_run[qb][i], fmaxf(mh0[r], mh1[r]));
                f[qb][i] = __expf(m_run[qb][i] - mnew);
                m_run[qb][i] = mnew;
                p[qb][0][i] = __expf(sc[qb][0][i] - mnew);
                p[qb][1][i] = __expf(sc[qb][1][i] - mnew);
                float ls = p[qb][0][i] + p[qb][1][i];
                #pragma unroll
                for (int off = 1; off < 16; off <<= 1) ls += __shfl_xor(ls, off);
                lsum[qb][i] = ls;
            }
        if (l15 == 0) {
            float* lh = kh ? lh1 : lh0;
            #pragma unroll
            for (int qb = 0; qb < 2; ++qb)
                #pragma unroll
                for (int i = 0; i < 4; ++i)
                    lh[qh * 32 + qb * 16 + h4 * 4 + i] = lsum[qb][i];
            if (kh == 0)
                #pragma unroll
                for (int qb = 0; qb < 2; ++qb)
                    #pragma unroll
                    for (int i = 0; i < 4; ++i)
                        frow[qh * 32 + qb * 16 + h4 * 4 + i] = f[qb][i];
        }
        #pragma unroll
        for (int qb = 0; qb < 2; ++qb)
            #pragma unroll
            for (int kcb = 0; kcb < 2; ++kcb) {
                const int kk = kh * 32 + kcb * 16 + l15;
                const int qq = qh * 32 + qb * 16 + h4 * 4;
                *(u32*)&PTb[kk * 66 + qq]     = packbf(p[qb][kcb][0], p[qb][kcb][1]);
                *(u32*)&PTb[kk * 66 + qq + 2] = packbf(p[qb][kcb][2], p[qb][kcb][3]);
            }
        __syncthreads();                          // D: P^T, frow, lhalf visible

        // ---- running denominator ----
        {
            const float* lhx = kh ? lh0 : lh1;    // other half's sums
            #pragma unroll
            for (int qb = 0; qb < 2; ++qb)
                #pragma unroll
                for (int i = 0; i < 4; ++i) {
                    const int r = qh * 32 + qb * 16 + h4 * 4 + i;
                    l_run[qb][i] = l_run[qb][i] * f[qb][i] + lsum[qb][i] + lhx[r];
                }
        }

        // ---- PV: o^T += V^T * P^T ----
        float fq[2];
        #pragma unroll
        for (int qb = 0; qb < 2; ++qb) fq[qb] = frow[qh * 32 + qb * 16 + l15];
        #pragma unroll
        for (int db = 0; db < 2; ++db)
            #pragma unroll
            for (int qb = 0; qb < 2; ++qb)
                oacc[db][qb] *= fq[qb];
        #pragma unroll
        for (int kc = 0; kc < 2; ++kc) {
            short8b vf[2];
            #pragma unroll
            for (int db = 0; db < 2; ++db)
                vf[db] = *(const short8b*)&Vt[(kh * 32 + db * 16 + l15) * 80 + kc * 32 + h4 * 8];
            union { short8b v; u16 u[8]; } pf[2];
            #pragma unroll
            for (int qb = 0; qb < 2; ++qb) {
                const int qq = qh * 32 + qb * 16 + l15;
                #pragma unroll
                for (int j = 0; j < 8; ++j)
                    pf[qb].u[j] = PTb[(kc * 32 + h4 * 8 + j) * 66 + qq];
            }
            #pragma unroll
            for (int db = 0; db < 2; ++db)
                #pragma unroll
                for (int qb = 0; qb < 2; ++qb)
                    oacc[db][qb] = __builtin_amdgcn_mfma_f32_16x16x32_bf16(
                        vf[db], pf[qb].v, oacc[db][qb], 0, 0, 0);
        }
        __syncthreads();                          // A': PV done, buffers free
    }

    // epilogue: unnormalized o^T partial + (m,l)
    float* ob = (sp == 0) ? op0 : ((sp == 1) ? op1 : op2);
    #pragma unroll
    for (int db = 0; db < 2; ++db)
        #pragma unroll
        for (int qb = 0; qb < 2; ++qb) {
            const int qq = q0 + qh * 32 + qb * 16 + l15;
            const int d0 = h * DH + kh * 32 + db * 16 + h4 * 4;
            *(f32x4*)&ob[(size_t)qq * DIM + d0] = oacc[db][qb];
        }
    if (kh == 0 && l15 == 0) {
        #pragma unroll
        for (int qb = 0; qb < 2; ++qb)
            #pragma unroll
            for (int i = 0; i < 4; ++i) {
                const int r = qh * 32 + qb * 16 + h4 * 4 + i;
                mpart[((size_t)sp * NN + q0 + r) * NH + h] = m_run[qb][i];
                lpart[((size_t)sp * NN + q0 + r) * NH + h] = l_run[qb][i];
            }
    }
}

// merge the 3 partials (in-place into o0 is safe: thread-private float4s)
__global__ __launch_bounds__(256) void attn_combine(
    const float* o0, const float* __restrict__ o1, const float* __restrict__ o2,
    const float* __restrict__ mp, const float* __restrict__ lp,
    float* out)
{
    const int gid = blockIdx.x * 256 + threadIdx.x;
    const int row = gid >> 6;
    const int c4  = (gid & 63) * 4;
    const int h   = c4 >> 6;
    const float m0 = mp[row * NH + h];
    const float m1 = mp[(NN + row) * NH + h];
    const float m2 = mp[(2 * NN + row) * NH + h];
    const float M  = fmaxf(fmaxf(m0, m1), m2);
    const float w0 = __expf(m0 - M), w1 = __expf(m1 - M), w2 = __expf(m2 - M);
    const float inv = 1.f / (lp[row * NH + h] * w0 +
                             lp[(NN + row) * NH + h] * w1 +
                             lp[(2 * NN + row) * NH + h] * w2);
    const float4 a = *(const float4*)&o0[(size_t)row * DIM + c4];
    const float4 b = *(const float4*)&o1[(size_t)row * DIM + c4];
    const float4 c = *(const float4*)&o2[(size_t)row * DIM + c4];
    float4 r;
    r.x = (a.x * w0 + b.x * w1 + c.x * w2) * inv;
    r.y = (a.y * w0 + b.y * w1 + c.y * w2) * inv;
    r.z = (a.z * w0 + b.z * w1 + c.z * w2) * inv;
    r.w = (a.w * w0 + b.w * w1 + c.w * w2) * inv;
    *(float4*)&out[(size_t)row * DIM + c4] = r;
}

// ---------------- per-node group adapter ----------------
__global__ __launch_bounds__(64) void adapter_kernel(
    const float* __restrict__ feats, const int* __restrict__ grp,
    const float* __restrict__ AW1, const float* __restrict__ Ab1,
    const float* __restrict__ AW2, const float* __restrict__ Ab2,
    float* __restrict__ out)
{
    const int n = blockIdx.x;
    const int lane = threadIdx.x;
    __shared__ float f[F1D];
    f[lane]      = feats[(size_t)n * F1D + lane];
    f[lane + 64] = feats[(size_t)n * F1D + 64 + lane];
    __syncthreads();
    const int g = grp[n];
    const float* W1 = AW1 + (size_t)g * F1D * AD;
    const int a = lane & 31;
    const int half = lane >> 5;
    float hsum = 0.f;
    for (int d = 0; d < 64; ++d)
        hsum = fmaf(f[half * 64 + d], W1[(half * 64 + d) * AD + a], hsum);
    hsum += __shfl_xor(hsum, 32);
    hsum = fmaxf(hsum + Ab1[g * AD + a], 0.f);
    float p = hsum * AW2[g * AD + a];
    #pragma unroll
    for (int mm = 1; mm < 32; mm <<= 1) p += __shfl_xor(p, mm);
    if (lane == 0) out[n] = p + Ab2[g];
}

// ---------------- host-side orchestration ----------------
extern "C" void kernel_launch(void* const* d_in, const int* in_sizes, int n_in,
                              void* d_out, int out_size, void* d_ws, size_t ws_size,
                              hipStream_t stream)
{
    const float* x_in   = (const float*)d_in[0];
    const float* eattr  = (const float*)d_in[1];
    const float* Wself  = (const float*)d_in[2];
    const float* Wnbr   = (const float*)d_in[3];
    const float* convb  = (const float*)d_in[4];
    const float* gamma  = (const float*)d_in[5];
    const float* beta   = (const float*)d_in[6];
    const float* bnmean = (const float*)d_in[7];
    const float* bnvar  = (const float*)d_in[8];
    const float* Wqkv   = (const float*)d_in[9];
    const float* bqkv   = (const float*)d_in[10];
    const float* Wo     = (const float*)d_in[11];
    const float* bo     = (const float*)d_in[12];
    const float* fc1W   = (const float*)d_in[13];
    const float* fc1b   = (const float*)d_in[14];
    const float* AW1    = (const float*)d_in[15];
    const float* Ab1    = (const float*)d_in[16];
    const float* AW2    = (const float*)d_in[17];
    const float* Ab2    = (const float*)d_in[18];
    const int*   eidx   = (const int*)d_in[19];
    const int*   grp    = (const int*)d_in[20];
    const int* srcArr = eidx;
    const int* dstArr = eidx + NE;

    float* fws = (float*)d_ws;
    const size_t NM = (size_t)NN * DIM;
    float* bufA   = fws;                 // x L0 / x L2 (residual)
    float* bufB   = fws + NM;            // agg scratch; attn op0; combined o
    float* bufC   = fws + 2 * NM;        // x L1; attn op1
    float* bufD   = fws + 3 * NM;        // attn op2; Wo out
    float* feats  = fws + 4 * NM;        // NN x F1D = NM/2
    float* mpart  = fws + 4 * NM + NM / 2;        // [3][NN][NH]
    float* lpart  = mpart + 3 * NN * NH;
    u16* qhi = (u16*)(lpart + 3 * NN * NH);       // NN*DIM u16 each
    u16* qlo = qhi + NM;
    u16* khi = qlo + NM;
    u16* klo = khi + NM;
    u16* vt  = klo + NM;                          // [DIM][NN]
    int*   esrc = (int*)(vt + NM);                // NE
    float* ewt  = (float*)(esrc + NE);            // NE
    int* off    = (int*)(ewt + NE);               // NN+1
    int* cur    = off + NN + 1;                   // NN
    float* outp = (float*)d_out;

    // CSR build
    hipMemsetAsync(cur, 0, NN * sizeof(int), stream);
    csr_count<<<NE / 256, 256, 0, stream>>>(dstArr, cur);
    csr_scan<<<1, 64, 0, stream>>>(cur, off);
    hipMemsetAsync(cur, 0, NN * sizeof(int), stream);
    csr_fill<<<NE / 256, 256, 0, stream>>>(dstArr, srcArr, eattr, off, cur, esrc, ewt);

    const dim3 gg(DIM / 64, NN / 64);

    // conv layer 0: x_in -> bufA
    agg_kernel<false><<<NN / 4, 256, 0, stream>>>(x_in, esrc, ewt, off, bufB);
    gemm_kernel<EPI_BNELU, true><<<gg, 256, 0, stream>>>(
        x_in, Wself, bufB, Wnbr, convb, gamma, beta, bnmean, bnvar,
        nullptr, bufA, DIM, DIM, nullptr, nullptr, nullptr, nullptr, nullptr);
    // conv layer 1: bufA -> bufC
    agg_kernel<false><<<NN / 4, 256, 0, stream>>>(bufA, esrc, ewt, off, bufB);
    gemm_kernel<EPI_BNELU, true><<<gg, 256, 0, stream>>>(
        bufA, Wself + DIM * DIM, bufB, Wnbr + DIM * DIM, convb + DIM,
        gamma + DIM, beta + DIM, bnmean + DIM, bnvar + DIM,
        nullptr, bufC, DIM, DIM, nullptr, nullptr, nullptr, nullptr, nullptr);
    // conv layer 2 (edge-weighted): bufC -> bufA
    agg_kernel<true><<<NN / 4, 256, 0, stream>>>(bufC, esrc, ewt, off, bufB);
    gemm_kernel<EPI_BIAS, true><<<gg, 256, 0, stream>>>(
        bufC, Wself + 2 * DIM * DIM, bufB, Wnbr + 2 * DIM * DIM, convb + 2 * DIM,
        nullptr, nullptr, nullptr, nullptr, nullptr, bufA, DIM, DIM,
        nullptr, nullptr, nullptr, nullptr, nullptr);

    // fused QKV projection -> bf16 hi/lo Q,K + V^T
    gemm_kernel<EPI_BIAS, false, true><<<dim3(3 * DIM / 64, NN / 64), 256, 0, stream>>>(
        bufA, Wqkv, nullptr, nullptr, bqkv,
        nullptr, nullptr, nullptr, nullptr, nullptr, nullptr, DIM, DIM,
        qhi, qlo, khi, klo, vt);

    // MFMA flash attention (3-way key split) -> partials, combine -> bufB
    attn_kernel<<<dim3(NN / QB, NH, NSPLIT), 256, 0, stream>>>(
        qhi, qlo, khi, klo, vt, bufB, bufC, bufD, mpart, lpart);
    attn_combine<<<NN * DIM / 4 / 256, 256, 0, stream>>>(
        bufB, bufC, bufD, mpart, lpart, bufB);

    // output projection + residual: bufD = bufA + bufB @ Wo + bo
    gemm_kernel<EPI_BIAS_RES, false><<<gg, 256, 0, stream>>>(
        bufB, Wo, nullptr, nullptr, bo,
        nullptr, nullptr, nullptr, nullptr, bufA, bufD, DIM, DIM,
        nullptr, nullptr, nullptr, nullptr, nullptr);

    // fc1 + ELU: feats = elu(bufD @ fc1W + fc1b)
    gemm_kernel<EPI_BIAS_ELU, false><<<dim3(F1D / 64, NN / 64), 256, 0, stream>>>(
        bufD, fc1W, nullptr, nullptr, fc1b,
        nullptr, nullptr, nullptr, nullptr, nullptr, feats, DIM, F1D,
        nullptr, nullptr, nullptr, nullptr, nullptr);

    // adapter routing -> out
    adapter_kernel<<<NN, 64, 0, stream>>>(feats, grp, AW1, Ab1, AW2, Ab2, outp);
}